// Round 9
// baseline (4742.962 us; speedup 1.0000x reference)
//
#include <hip/hip_runtime.h>
#include <math.h>

typedef float v2f __attribute__((ext_vector_type(2)));
typedef float v4f __attribute__((ext_vector_type(4)));

#define NMAT 32768
#define SW1 5          // pass-1 sweeps (hedged; trim once passing)
#define SW2 3          // pass-2 sweeps (warm start, hedged)
#define SW_SINGLE 10   // single-matrix eigs
#define SP 34          // padded row stride for single-wave LDS matrices

// workspace float offsets
#define WS_G    0
#define WS_GS   1024
#define WS_GIS  2048
#define WS_GT   3072
#define WS_K    4096
#define WS_C    5120
#define WS_S1   6144
#define WS_S2   6145
#define WS_P    6146
#define WS_TOTAL 6400

__device__ __forceinline__ int swz(int r, int c) {
    return r * 32 + 2 * ((c >> 1) ^ (r & 15)) + (c & 1);
}
__device__ __forceinline__ void wave_fence() {
    asm volatile("s_waitcnt lgkmcnt(0)" ::: "memory");
}
__device__ __forceinline__ v2f mk2(float a, float b) { v2f r; r.x = a; r.y = b; return r; }

// xor-shuffle: CTRL!=0 -> VALU DPP quad_perm (masks 1,2,3 only — proven in r7);
// CTRL==0 -> DS shuffle.
template<int CTRL>
__device__ __forceinline__ float xsh(float x, int m) {
    if constexpr (CTRL != 0) {
        return __int_as_float(__builtin_amdgcn_update_dpp(
            __float_as_int(x), __float_as_int(x), CTRL, 0xF, 0xF, true));
    } else {
        return __shfl_xor(x, m, 64);
    }
}

__device__ __forceinline__ float nrm16(const v2f (&v)[16]) {
    v2f n0 = v[0] * v[0], n1 = v[1] * v[1], n2 = v[2] * v[2], n3 = v[3] * v[3];
    #pragma unroll
    for (int j = 4; j < 16; j += 4) {
        n0 += v[j] * v[j];     n1 += v[j + 1] * v[j + 1];
        n2 += v[j + 2] * v[j + 2]; n3 += v[j + 3] * v[j + 3];
    }
    v2f nt = (n0 + n1) + (n2 + n3);
    return nt.x + nt.y;
}

// ---------------------------------------------------------------------------
// Symmetric fast-Givens rotation on column pair (X,Y). Role-symmetric with a
// deterministic d==0 tie-break via `low` (partner lane has !low -> t flips).
// ---------------------------------------------------------------------------
__device__ __forceinline__ void rot2(v2f (&X)[16], v2f (&Y)[16],
                                     float& dnX, float& dnY,
                                     float& sX, float& rsX,
                                     float& sY, float& rsY, bool low) {
    v2f p0 = X[0] * Y[0], p1 = X[1] * Y[1], p2 = X[2] * Y[2], p3 = X[3] * Y[3];
    #pragma unroll
    for (int j = 4; j < 16; j += 4) {
        p0 += X[j] * Y[j];         p1 += X[j + 1] * Y[j + 1];
        p2 += X[j + 2] * Y[j + 2]; p3 += X[j + 3] * Y[j + 3];
    }
    v2f pt = (p0 + p1) + (p2 + p3);
    const float raw = pt.x + pt.y;
    const float apq = (sX * sY) * raw;
    const float b   = apq + apq;
    const float d   = dnY - dnX;
    const float r2  = __builtin_fmaf(d, d, b * b);
    const float sr  = __builtin_amdgcn_sqrtf(r2);
    const float u   = fmaxf(fabsf(d) + sr, 1e-30f);
    const bool  neg = (d < 0.f) || (d == 0.f && !low);   // tie-safe sign
    const float t   = (neg ? -b : b) * __builtin_amdgcn_rcpf(u);
    const float s1f = __builtin_fmaf(t, t, 1.f);
    const float c   = __builtin_amdgcn_rsqf(s1f);
    const float rc  = c * s1f;
    const float gX  = -t * (sY * rsX);
    const float gY  =  t * (sX * rsY);
    const v2f gX2 = {gX, gX}, gY2 = {gY, gY};
    #pragma unroll
    for (int j = 0; j < 16; ++j) {
        const v2f yo = Y[j];
        Y[j] = yo + gY2 * X[j];
        X[j] = X[j] + gX2 * yo;
    }
    dnX = __builtin_fmaf(-t, apq, dnX);
    dnY = __builtin_fmaf( t, apq, dnY);
    sX *= c; rsX *= rc;
    sY *= c; rsY *= rc;
}

// One tournament meeting vs group g^m: fetch partner's 2 columns (+scalars),
// 4 cross rotations (order differs from partner only by commuting disjoint
// rotations; parameters bit-consistent).
template<int CTRL>
__device__ __forceinline__ void meeting(v2f (&v0)[16], v2f (&v1)[16],
                                        float& dn0, float& dn1,
                                        float& s0, float& rs0,
                                        float& s1_, float& rs1, int m, int g) {
    const bool low = g < (g ^ m);
    v2f c0[16], c1[16];
    #pragma unroll
    for (int j = 0; j < 16; ++j) {
        c0[j].x = xsh<CTRL>(v0[j].x, m);
        c0[j].y = xsh<CTRL>(v0[j].y, m);
    }
    float cdn0 = xsh<CTRL>(dn0, m), cs0 = xsh<CTRL>(s0, m), crs0 = xsh<CTRL>(rs0, m);
    #pragma unroll
    for (int j = 0; j < 16; ++j) {
        c1[j].x = xsh<CTRL>(v1[j].x, m);
        c1[j].y = xsh<CTRL>(v1[j].y, m);
    }
    float cdn1 = xsh<CTRL>(dn1, m), cs1 = xsh<CTRL>(s1_, m), crs1 = xsh<CTRL>(rs1, m);
    rot2(v0, c0, dn0, cdn0, s0, rs0, cs0, crs0, low);
    rot2(v1, c1, dn1, cdn1, s1_, rs1, cs1, crs1, low);
    rot2(v0, c1, dn0, cdn1, s0, rs0, cs1, crs1, low);
    rot2(v1, c0, dn1, cdn0, s1_, rs1, cs0, crs0, low);
}

// ---------------------------------------------------------------------------
// Blocked one-sided Jacobi: lane owns cols {2g,2g+1}; 16 lanes/matrix;
// 4 matrices/wave. 15 meetings/sweep (masks 1,2,3 on DPP; rest DS) + intra.
// ---------------------------------------------------------------------------
__device__ __forceinline__ void jacobi_blk(v2f (&v0)[16], v2f (&v1)[16], int g,
                                           int sweeps, float& odn0, float& odn1) {
    #pragma unroll 1
    for (int sw = 0; sw < sweeps; ++sw) {
        float dn0 = nrm16(v0), dn1 = nrm16(v1);
        float s0 = 1.f, rs0 = 1.f, s1_ = 1.f, rs1 = 1.f;
        rot2(v0, v1, dn0, dn1, s0, rs0, s1_, rs1, true);  // intra pair
        meeting<0xB1>(v0, v1, dn0, dn1, s0, rs0, s1_, rs1, 1, g);
        meeting<0x4E>(v0, v1, dn0, dn1, s0, rs0, s1_, rs1, 2, g);
        meeting<0x1B>(v0, v1, dn0, dn1, s0, rs0, s1_, rs1, 3, g);
        #pragma unroll 1
        for (int m = 4; m <= 15; ++m)
            meeting<0>(v0, v1, dn0, dn1, s0, rs0, s1_, rs1, m, g);
        const v2f f0 = {s0, s0}, f1 = {s1_, s1_};
        #pragma unroll
        for (int j = 0; j < 16; ++j) { v0[j] *= f0; v1[j] *= f1; }
    }
    odn0 = nrm16(v0);
    odn1 = nrm16(v1);
}

// ---------------------------------------------------------------------------
// Single-wave 1-col Jacobi (k_small_prep / k_karcher only) — r7-proven.
// ---------------------------------------------------------------------------
template<int CTRL>
__device__ __forceinline__ void jac_round(v2f (&v)[16], int col, int m,
                                          float& dn, float& sc, float& rsc) {
    const float dnq = xsh<CTRL>(dn, m);
    const float dq  = xsh<CTRL>(sc, m);
    v2f o[16];
    #pragma unroll
    for (int j = 0; j < 16; ++j) {
        o[j].x = xsh<CTRL>(v[j].x, m);
        o[j].y = xsh<CTRL>(v[j].y, m);
    }
    v2f p0 = v[0] * o[0], p1 = v[1] * o[1], p2 = v[2] * o[2], p3 = v[3] * o[3];
    #pragma unroll
    for (int j = 4; j < 16; j += 4) {
        p0 += v[j] * o[j];     p1 += v[j + 1] * o[j + 1];
        p2 += v[j + 2] * o[j + 2]; p3 += v[j + 3] * o[j + 3];
    }
    v2f pt = (p0 + p1) + (p2 + p3);
    const float raw = pt.x + pt.y;
    const bool  isp = col < (col ^ m);
    const float apq = (sc * dq) * raw;
    const float b   = apq + apq;
    const float d   = isp ? (dnq - dn) : (dn - dnq);
    const float r2  = __builtin_fmaf(d, d, b * b);
    const float sr  = __builtin_amdgcn_sqrtf(r2);
    const float u   = fmaxf(fabsf(d) + sr, 1e-30f);
    const float t   = (d < 0.f ? -b : b) * __builtin_amdgcn_rcpf(u);
    const float s1  = __builtin_fmaf(t, t, 1.f);
    const float c   = __builtin_amdgcn_rsqf(s1);
    const float gam = t * (dq * rsc);
    const float gs  = isp ? -gam : gam;
    const v2f gs2 = {gs, gs};
    #pragma unroll
    for (int j = 0; j < 16; ++j) v[j] += gs2 * o[j];
    sc *= c; rsc *= c * s1;
    dn = __builtin_fmaf(isp ? -t : t, apq, dn);
}

__device__ __forceinline__ float jacobi_fg(v2f (&v)[16], int col, int sweeps) {
    #pragma unroll 1
    for (int sweep = 0; sweep < sweeps; ++sweep) {
        float dn = nrm16(v);
        float sc = 1.f, rsc = 1.f;
        jac_round<0xB1>(v, col, 1, dn, sc, rsc);
        jac_round<0x4E>(v, col, 2, dn, sc, rsc);
        jac_round<0x1B>(v, col, 3, dn, sc, rsc);
        #pragma unroll 1
        for (int m = 4; m < 32; ++m) jac_round<0>(v, col, m, dn, sc, rsc);
        const v2f s2 = {sc, sc};
        #pragma unroll
        for (int j = 0; j < 16; ++j) v[j] *= s2;
    }
    return nrm16(v);
}

__device__ __forceinline__ void put_col(float* L, const v2f (&w)[16], int col) {
    #pragma unroll
    for (int j = 0; j < 16; ++j) {
        L[(2 * j) * SP + col]     = w[j].x;
        L[(2 * j + 1) * SP + col] = w[j].y;
    }
}

__device__ __forceinline__ void colmm(const float* L, const v2f (&y)[16], v2f (&z)[16]) {
    #pragma unroll
    for (int i = 0; i < 32; ++i) {
        v2f acc = {0.f, 0.f};
        #pragma unroll
        for (int q = 0; q < 16; ++q) {
            v2f mm = *(const v2f*)&L[i * SP + 2 * q];
            acc += mm * y[q];
        }
        float zi = acc.x + acc.y;
        if (i & 1) z[i >> 1].y = zi; else z[i >> 1].x = zi;
    }
}

__device__ __forceinline__ void recon_col(const float* LW, float coef, int col,
                                          int base, v2f (&z)[16]) {
    float rv[32];
    #pragma unroll
    for (int k = 0; k < 32; ++k) rv[k] = LW[col * SP + k];
    v2f y[16];
    #pragma unroll
    for (int q = 0; q < 16; ++q) {
        y[q].x = __shfl(coef, base | (2 * q), 64)     * rv[2 * q];
        y[q].y = __shfl(coef, base | (2 * q + 1), 64) * rv[2 * q + 1];
    }
    colmm(LW, y, z);
}

// ---------------------------------------------------------------------------
// K1: arithmetic mean -> ws[WS_G]
// ---------------------------------------------------------------------------
__global__ __launch_bounds__(256) void k_mean(const float* __restrict__ X,
                                              float* __restrict__ ws) {
    const int t = threadIdx.x;
    const size_t base = (size_t)blockIdx.x * 64 * 1024;
    float4 a = {0.f, 0.f, 0.f, 0.f};
    for (int m = 0; m < 64; ++m) {
        float4 f = *(const float4*)&X[base + (size_t)m * 1024 + t * 4];
        a.x += f.x; a.y += f.y; a.z += f.z; a.w += f.w;
    }
    const float s = 1.0f / (float)NMAT;
    atomicAdd(ws + WS_G + 4 * t + 0, a.x * s);
    atomicAdd(ws + WS_G + 4 * t + 1, a.y * s);
    atomicAdd(ws + WS_G + 4 * t + 2, a.z * s);
    atomicAdd(ws + WS_G + 4 * t + 3, a.w * s);
}

// ---------------------------------------------------------------------------
// K2: block 0: eig(G) -> Gs, Gis.  block 1: eig(B) -> C = B^{1/2} R.
// ---------------------------------------------------------------------------
__global__ __launch_bounds__(64) void k_small_prep(const float* __restrict__ R,
                                                   const float* __restrict__ B,
                                                   float* __restrict__ ws) {
    __shared__ float LW[32 * SP];
    const int lane = threadIdx.x;
    const int col  = lane & 31;
    const int base = lane & 32;
    if (blockIdx.x == 0) {
        v2f w[16];
        #pragma unroll
        for (int j = 0; j < 16; ++j) {
            w[j].x = ws[WS_G + (2 * j) * 32 + col];
            w[j].y = ws[WS_G + (2 * j + 1) * 32 + col];
        }
        const float dn = jacobi_fg(w, col, SW_SINGLE);
        put_col(LW, w, col);
        __syncthreads();
        const float lam = __builtin_amdgcn_sqrtf(dn);
        const float cs  = __builtin_amdgcn_sqrtf(lam) * __builtin_amdgcn_rcpf(dn);
        const float cis = __builtin_amdgcn_rsqf(lam)  * __builtin_amdgcn_rcpf(dn);
        v2f z[16];
        recon_col(LW, cs, col, base, z);
        #pragma unroll
        for (int j = 0; j < 16; ++j) {
            ws[WS_GS + (2 * j) * 32 + col]     = z[j].x;
            ws[WS_GS + (2 * j + 1) * 32 + col] = z[j].y;
        }
        recon_col(LW, cis, col, base, z);
        #pragma unroll
        for (int j = 0; j < 16; ++j) {
            ws[WS_GIS + (2 * j) * 32 + col]     = z[j].x;
            ws[WS_GIS + (2 * j + 1) * 32 + col] = z[j].y;
        }
    } else {
        v2f w[16];
        #pragma unroll
        for (int j = 0; j < 16; ++j) {
            w[j].x = B[(2 * j) * 32 + col];
            w[j].y = B[(2 * j + 1) * 32 + col];
        }
        const float dn = jacobi_fg(w, col, SW_SINGLE);
        put_col(LW, w, col);
        __syncthreads();
        const float lam = __builtin_amdgcn_sqrtf(dn);
        const float cbs = __builtin_amdgcn_sqrtf(lam) * __builtin_amdgcn_rcpf(dn);
        v2f bs[16];
        recon_col(LW, cbs, col, base, bs);
        __syncthreads();
        put_col(LW, bs, col);
        __syncthreads();
        v2f r[16];
        #pragma unroll
        for (int j = 0; j < 16; ++j) {
            r[j].x = R[(2 * j) * 32 + col];
            r[j].y = R[(2 * j + 1) * 32 + col];
        }
        v2f c[16];
        colmm(LW, r, c);
        #pragma unroll
        for (int j = 0; j < 16; ++j) {
            ws[WS_C + (2 * j) * 32 + col]     = c[j].x;
            ws[WS_C + (2 * j + 1) * 32 + col] = c[j].y;
        }
    }
}

// ---------------------------------------------------------------------------
// K3 (pass 1): M = Gis X Gis; blocked Jacobi (4 mat/wave); W1 -> w1out;
// GT/S1/S2 accumulation (4-stage take-turns tile).
// ---------------------------------------------------------------------------
__global__ __launch_bounds__(256, 3) void k_batch_log(const float* __restrict__ X,
                                                      float* __restrict__ w1out,
                                                      float* __restrict__ ws) {
    __shared__ float HL[1024];       // Gis, pair-swizzled
    __shared__ float TW[4][1024];    // per-wave take-turns W tile
    __shared__ float GB[4][4][32];   // per-wave, per-stage g coefficients
    __shared__ float ACC[1024];
    __shared__ float S1B, S2B;
    const int tid = threadIdx.x;
    if (tid == 0) { S1B = 0.f; S2B = 0.f; }
    for (int e = tid; e < 1024; e += 256) {
        int r = e >> 5, c = e & 31;
        HL[swz(r, c)] = ws[WS_GIS + e];
        ACC[e] = 0.f;
    }
    __syncthreads();

    const int lane = tid & 63;
    const int wv   = tid >> 6;
    const int q    = lane >> 4;          // matrix quarter within wave
    const int g    = lane & 15;          // group (owns cols 2g, 2g+1)
    const int c0   = 2 * g, c1 = 2 * g + 1;
    const size_t gm = (size_t)blockIdx.x * 16 + wv * 4 + q;
    const float* Xm = X + gm * 1024;
    float* tw = TW[wv];

    // h cols = Gis cols c0,c1 (via symmetry: rows c0,c1)
    v2f h0[16], h1[16];
    const int e0 = c0 & 15, e1 = c1 & 15;
    #pragma unroll
    for (int p = 0; p < 16; ++p) {
        h0[p] = *(const v2f*)&HL[c0 * 32 + 2 * (p ^ e0)];
        h1[p] = *(const v2f*)&HL[c1 * 32 + 2 * (p ^ e1)];
    }

    // t = X * h (dual columns)
    v2f t0[16], t1[16];
    #pragma unroll
    for (int i = 0; i < 32; ++i) {
        const float4* row = (const float4*)(Xm + i * 32);
        v2f a0 = {0.f, 0.f}, a1 = {0.f, 0.f};
        #pragma unroll
        for (int q8 = 0; q8 < 8; ++q8) {
            float4 f = row[q8];
            v2f lo = {f.x, f.y}, hi = {f.z, f.w};
            a0 += lo * h0[2 * q8] + hi * h0[2 * q8 + 1];
            a1 += lo * h1[2 * q8] + hi * h1[2 * q8 + 1];
        }
        float u0 = a0.x + a0.y, u1 = a1.x + a1.y;
        if (i & 1) { t0[i >> 1].y = u0; t1[i >> 1].y = u1; }
        else       { t0[i >> 1].x = u0; t1[i >> 1].x = u1; }
    }
    // v = Gis * t (dual)
    v2f v0[16], v1[16];
    #pragma unroll
    for (int i = 0; i < 32; ++i) {
        const int twi = i & 15;
        v2f a0 = {0.f, 0.f}, a1 = {0.f, 0.f};
        #pragma unroll
        for (int q8 = 0; q8 < 8; ++q8) {
            v4f f = *(const v4f*)&HL[i * 32 + 4 * q8];
            v2f lo = {f.x, f.y}, hi = {f.z, f.w};
            a0 += lo * t0[(2 * q8) ^ twi] + hi * t0[(2 * q8 + 1) ^ twi];
            a1 += lo * t1[(2 * q8) ^ twi] + hi * t1[(2 * q8 + 1) ^ twi];
        }
        float u0 = a0.x + a0.y, u1 = a1.x + a1.y;
        if (i & 1) { v0[i >> 1].y = u0; v1[i >> 1].y = u1; }
        else       { v0[i >> 1].x = u0; v1[i >> 1].x = u1; }
    }

    float dn0, dn1;
    jacobi_blk(v0, v1, g, SW1, dn0, dn1);

    // W1 -> global (row-pair v2f stores)
    float* op = w1out + gm * 1024 + c0;
    #pragma unroll
    for (int j = 0; j < 16; ++j) {
        *(v2f*)&op[(2 * j) * 32]     = mk2(v0[j].x, v1[j].x);
        *(v2f*)&op[(2 * j + 1) * 32] = mk2(v0[j].y, v1[j].y);
    }

    // log-eigen stats
    const float ls0 = 0.5f * logf(dn0), ls1 = 0.5f * logf(dn1);
    const float invN = 1.0f / (float)NMAT;
    const float g0 = ls0 * __builtin_amdgcn_rcpf(dn0) * invN;
    const float g1 = ls1 * __builtin_amdgcn_rcpf(dn1) * invN;
    {
        float s1v = ls0 + ls1, s2v = ls0 * ls0 + ls1 * ls1;
        #pragma unroll
        for (int m = 32; m >= 1; m >>= 1) {
            s1v += __shfl_xor(s1v, m, 64);
            s2v += __shfl_xor(s2v, m, 64);
        }
        if (lane == 0) { atomicAdd(&S1B, s1v); atomicAdd(&S2B, s2v); }
    }

    // GT recon: 4-stage take-turns tile per wave
    float accR[16];
    #pragma unroll
    for (int i = 0; i < 16; ++i) accR[i] = 0.f;
    const int cc = lane & 31, half = lane >> 5;
    const int cm = cc & 15, cbase = cc * 32;

    #pragma unroll 1
    for (int s = 0; s < 4; ++s) {
        if (q == s) {
            #pragma unroll
            for (int j = 0; j < 16; ++j) {
                *(v2f*)&tw[(2 * j) * 32 + 2 * (g ^ ((2 * j) & 15))]         = mk2(v0[j].x, v1[j].x);
                *(v2f*)&tw[(2 * j + 1) * 32 + 2 * (g ^ ((2 * j + 1) & 15))] = mk2(v0[j].y, v1[j].y);
            }
            *(v2f*)&GB[wv][s][c0] = mk2(g0, g1);
        }
        wave_fence();
        v2f gr[16];
        #pragma unroll
        for (int p2 = 0; p2 < 16; ++p2) {
            v2f wr = *(const v2f*)&tw[cbase + 2 * (p2 ^ cm)];
            v2f gg = *(const v2f*)&GB[wv][s][2 * p2];
            gr[p2] = gg * wr;
        }
        #pragma unroll
        for (int i = 0; i < 16; ++i) {
            const int r = half * 16 + i;
            const int rw = r & 15;
            v2f acc = {0.f, 0.f};
            #pragma unroll
            for (int q8 = 0; q8 < 8; ++q8) {
                v4f f = *(const v4f*)&tw[r * 32 + 4 * q8];
                v2f lo = {f.x, f.y}, hi = {f.z, f.w};
                acc += lo * gr[(2 * q8) ^ rw] + hi * gr[(2 * q8 + 1) ^ rw];
            }
            accR[i] += acc.x + acc.y;
        }
        wave_fence();
    }
    #pragma unroll
    for (int i = 0; i < 16; ++i)
        atomicAdd(&ACC[(half * 16 + i) * 32 + cc], accR[i]);
    __syncthreads();
    for (int e = tid; e < 1024; e += 256) atomicAdd(ws + WS_GT + e, ACC[e]);
    if (tid == 0) {
        atomicAdd(ws + WS_S1, S1B * invN);
        atomicAdd(ws + WS_S2, S2B * invN);
    }
}

// ---------------------------------------------------------------------------
// K4: E = exp(GT); Gn = Gs E Gs; Gh = Gn^{-1/2}; K = Gh*Gs; p from S1,S2.
// ---------------------------------------------------------------------------
__global__ __launch_bounds__(64) void k_karcher(float* __restrict__ ws) {
    __shared__ float LA[32 * SP];
    __shared__ float LB[32 * SP];
    const int lane = threadIdx.x;
    const int col  = lane & 31;
    const int base = lane & 32;

    for (int e = lane; e < 1024; e += 64)
        LB[(e >> 5) * SP + (e & 31)] = ws[WS_GS + e];
    v2f gsc[16];
    #pragma unroll
    for (int j = 0; j < 16; ++j) {
        gsc[j].x = ws[WS_GS + (2 * j) * 32 + col];
        gsc[j].y = ws[WS_GS + (2 * j + 1) * 32 + col];
    }
    v2f w[16];
    #pragma unroll
    for (int j = 0; j < 16; ++j) {
        w[j].x = ws[WS_GT + (2 * j) * 32 + col];
        w[j].y = ws[WS_GT + (2 * j + 1) * 32 + col];
    }
    v2f cn2 = {0.f, 0.f};
    #pragma unroll
    for (int j = 0; j < 16; ++j) cn2 += w[j] * w[j];
    float fro2 = cn2.x + cn2.y;
    #pragma unroll
    for (int m = 16; m >= 1; m >>= 1) fro2 += __shfl_xor(fro2, m, 64);
    const float shift = __builtin_amdgcn_sqrtf(fro2) + 0.01f;
    #pragma unroll
    for (int j = 0; j < 16; ++j) {
        w[j].x += (2 * j     == col) ? shift : 0.f;
        w[j].y += (2 * j + 1 == col) ? shift : 0.f;
    }
    const float dn = jacobi_fg(w, col, SW_SINGLE);
    put_col(LA, w, col);
    __syncthreads();
    const float lam = __builtin_amdgcn_sqrtf(dn) - shift;
    const float ce  = expf(lam) * __builtin_amdgcn_rcpf(dn);
    v2f ec[16];
    recon_col(LA, ce, col, base, ec);
    __syncthreads();
    put_col(LA, ec, col);
    __syncthreads();
    v2f u[16], gn[16];
    colmm(LA, gsc, u);
    colmm(LB, u, gn);
    const float dn2 = jacobi_fg(gn, col, SW_SINGLE);
    __syncthreads();
    put_col(LA, gn, col);
    __syncthreads();
    const float lam2 = __builtin_amdgcn_sqrtf(dn2);
    const float ch   = __builtin_amdgcn_rsqf(lam2) * __builtin_amdgcn_rcpf(dn2);
    v2f gh[16];
    recon_col(LA, ch, col, base, gh);
    __syncthreads();
    put_col(LA, gh, col);
    __syncthreads();
    v2f kc[16];
    colmm(LA, gsc, kc);
    #pragma unroll
    for (int j = 0; j < 16; ++j) {
        ws[WS_K + (2 * j) * 32 + col]     = kc[j].x;
        ws[WS_K + (2 * j + 1) * 32 + col] = kc[j].y;
    }
    if (lane == 0) {
        const float S1  = ws[WS_S1];
        const float S2  = ws[WS_S2];
        const float var = S2 - S1 * S1 * 0.03125f;
        ws[WS_P] = __builtin_amdgcn_rsqf(var + 1e-5f);
    }
}

// ---------------------------------------------------------------------------
// K5 (fused warm+final): F = K W1 diag(lam1^{-1/2}); blocked Jacobi;
// Y = C W2 diag(lam^{(p-1)/2}); out = Y Y^T (4-stage take-turns tile).
// ---------------------------------------------------------------------------
__global__ __launch_bounds__(256, 3) void k_fused(float* __restrict__ out,
                                                  const float* __restrict__ ws) {
    __shared__ float KL[1024];
    __shared__ float CL[1024];
    __shared__ float TW[4][1024];
    const int tid = threadIdx.x;
    for (int e = tid; e < 1024; e += 256) {
        KL[e] = ws[WS_K + e];
        CL[e] = ws[WS_C + e];
    }
    __syncthreads();

    const int lane = tid & 63;
    const int wv   = tid >> 6;
    const int q    = lane >> 4;
    const int g    = lane & 15;
    const int c0   = 2 * g;
    const size_t gmbase = (size_t)blockIdx.x * 16 + wv * 4;
    const size_t gm = gmbase + q;
    float* tw = TW[wv];
    const float p = ws[WS_P];

    // own W1 cols (register transpose from row-pair v2f loads)
    const float* wp = out + gm * 1024 + c0;
    v2f v0[16], v1[16];
    #pragma unroll
    for (int j = 0; j < 16; ++j) {
        v2f la = *(const v2f*)&wp[(2 * j) * 32];
        v2f lb = *(const v2f*)&wp[(2 * j + 1) * 32];
        v0[j] = mk2(la.x, lb.x);
        v1[j] = mk2(la.y, lb.y);
    }
    const float nn0 = nrm16(v0), nn1 = nrm16(v1);
    const float sc0 = __builtin_amdgcn_rsqf(__builtin_amdgcn_sqrtf(nn0));
    const float sc1 = __builtin_amdgcn_rsqf(__builtin_amdgcn_sqrtf(nn1));
    v2f t0[16], t1[16];
    const v2f sv0 = {sc0, sc0}, sv1 = {sc1, sc1};
    #pragma unroll
    for (int j = 0; j < 16; ++j) { t0[j] = v0[j] * sv0; t1[j] = v1[j] * sv1; }

    // F cols = K * t (dual)
    #pragma unroll
    for (int i = 0; i < 32; ++i) {
        v2f a0 = {0.f, 0.f}, a1 = {0.f, 0.f};
        #pragma unroll
        for (int q8 = 0; q8 < 8; ++q8) {
            v4f f = *(const v4f*)&KL[i * 32 + 4 * q8];
            v2f lo = {f.x, f.y}, hi = {f.z, f.w};
            a0 += lo * t0[2 * q8] + hi * t0[2 * q8 + 1];
            a1 += lo * t1[2 * q8] + hi * t1[2 * q8 + 1];
        }
        float u0 = a0.x + a0.y, u1 = a1.x + a1.y;
        if (i & 1) { v0[i >> 1].y = u0; v1[i >> 1].y = u1; }
        else       { v0[i >> 1].x = u0; v1[i >> 1].x = u1; }
    }

    float dn0, dn1;
    jacobi_blk(v0, v1, g, SW2, dn0, dn1);   // dn = lambda (factor form)

    const float dj0 = exp2f(log2f(dn0) * 0.5f * (p - 1.0f));
    const float dj1 = exp2f(log2f(dn1) * 0.5f * (p - 1.0f));
    const v2f dv0 = {dj0, dj0}, dv1 = {dj1, dj1};
    #pragma unroll
    for (int j = 0; j < 16; ++j) { t0[j] = v0[j] * dv0; t1[j] = v1[j] * dv1; }

    // Y cols = C * t (dual)
    v2f y0[16], y1[16];
    #pragma unroll
    for (int i = 0; i < 32; ++i) {
        v2f a0 = {0.f, 0.f}, a1 = {0.f, 0.f};
        #pragma unroll
        for (int q8 = 0; q8 < 8; ++q8) {
            v4f f = *(const v4f*)&CL[i * 32 + 4 * q8];
            v2f lo = {f.x, f.y}, hi = {f.z, f.w};
            a0 += lo * t0[2 * q8] + hi * t0[2 * q8 + 1];
            a1 += lo * t1[2 * q8] + hi * t1[2 * q8 + 1];
        }
        float u0 = a0.x + a0.y, u1 = a1.x + a1.y;
        if (i & 1) { y0[i >> 1].y = u0; y1[i >> 1].y = u1; }
        else       { y0[i >> 1].x = u0; y1[i >> 1].x = u1; }
    }

    // out = Y Y^T, 4-stage take-turns tile
    const int cc = lane & 31, half = lane >> 5;
    const int cm = cc & 15, cbase = cc * 32;
    #pragma unroll 1
    for (int s = 0; s < 4; ++s) {
        if (q == s) {
            #pragma unroll
            for (int j = 0; j < 16; ++j) {
                *(v2f*)&tw[(2 * j) * 32 + 2 * (g ^ ((2 * j) & 15))]         = mk2(y0[j].x, y1[j].x);
                *(v2f*)&tw[(2 * j + 1) * 32 + 2 * (g ^ ((2 * j + 1) & 15))] = mk2(y0[j].y, y1[j].y);
            }
        }
        wave_fence();
        v2f yc[16];
        #pragma unroll
        for (int p2 = 0; p2 < 16; ++p2)
            yc[p2] = *(const v2f*)&tw[cbase + 2 * (p2 ^ cm)];
        const size_t gmo = gmbase + s;
        #pragma unroll
        for (int i = 0; i < 16; ++i) {
            const int r = half * 16 + i;
            const int rw = r & 15;
            v2f acc = {0.f, 0.f};
            #pragma unroll
            for (int q8 = 0; q8 < 8; ++q8) {
                v4f f = *(const v4f*)&tw[r * 32 + 4 * q8];
                v2f lo = {f.x, f.y}, hi = {f.z, f.w};
                acc += lo * yc[(2 * q8) ^ rw] + hi * yc[(2 * q8 + 1) ^ rw];
            }
            out[gmo * 1024 + r * 32 + cc] = acc.x + acc.y;
        }
        wave_fence();
    }
}

extern "C" void kernel_launch(void* const* d_in, const int* in_sizes, int n_in,
                              void* d_out, int out_size, void* d_ws, size_t ws_size,
                              hipStream_t stream) {
    const float* X = (const float*)d_in[0];
    const float* R = (const float*)d_in[1];
    const float* B = (const float*)d_in[2];
    float* out = (float*)d_out;
    float* ws  = (float*)d_ws;

    hipMemsetAsync(d_ws, 0, WS_TOTAL * sizeof(float), stream);
    k_mean<<<NMAT / 64, 256, 0, stream>>>(X, ws);
    k_small_prep<<<2, 64, 0, stream>>>(R, B, ws);
    k_batch_log<<<NMAT / 16, 256, 0, stream>>>(X, out, ws);
    k_karcher<<<1, 64, 0, stream>>>(ws);
    k_fused<<<NMAT / 16, 256, 0, stream>>>(out, ws);
}

// Round 10
// 1762.587 us; speedup vs baseline: 2.6909x; 2.6909x over previous
//
#include <hip/hip_runtime.h>
#include <math.h>

typedef float v2f __attribute__((ext_vector_type(2)));
typedef float v4f __attribute__((ext_vector_type(4)));

#define NMAT 32768
#define SW1 5          // pass-1 sweeps
#define SW2 3          // pass-2 sweeps (warm start)
#define SW_SINGLE 10   // single-matrix eigs
#define SP 34          // padded row stride for single-wave LDS matrices

// workspace float offsets
#define WS_G    0
#define WS_GS   1024
#define WS_GIS  2048
#define WS_GT   3072
#define WS_K    4096
#define WS_C    5120
#define WS_S1   6144
#define WS_S2   6145
#define WS_P    6146
#define WS_TOTAL 6400

__device__ __forceinline__ int swz(int r, int c) {
    return r * 32 + 2 * ((c >> 1) ^ (r & 15)) + (c & 1);
}
__device__ __forceinline__ void wave_fence() {
    asm volatile("s_waitcnt lgkmcnt(0)" ::: "memory");
}
__device__ __forceinline__ v2f mk2(float a, float b) { v2f r; r.x = a; r.y = b; return r; }

// xor-shuffle: CTRL!=0 -> VALU DPP quad_perm (masks 1,2,3); CTRL==0 -> DS.
template<int CTRL>
__device__ __forceinline__ float xsh(float x, int m) {
    if constexpr (CTRL != 0) {
        return __int_as_float(__builtin_amdgcn_update_dpp(
            __float_as_int(x), __float_as_int(x), CTRL, 0xF, 0xF, true));
    } else {
        return __shfl_xor(x, m, 64);
    }
}

__device__ __forceinline__ float nrm16(const v2f (&v)[16]) {
    v2f n0 = v[0] * v[0], n1 = v[1] * v[1], n2 = v[2] * v[2], n3 = v[3] * v[3];
    #pragma unroll
    for (int j = 4; j < 16; j += 4) {
        n0 += v[j] * v[j];     n1 += v[j + 1] * v[j + 1];
        n2 += v[j + 2] * v[j + 2]; n3 += v[j + 3] * v[j + 3];
    }
    v2f nt = (n0 + n1) + (n2 + n3);
    return nt.x + nt.y;
}

// ---------------------------------------------------------------------------
// Symmetric fast-Givens rotation on column pair (X,Y); deterministic d==0
// tie-break via `low` (partner lane computes !low -> t flips).
// ---------------------------------------------------------------------------
__device__ __forceinline__ void rot2(v2f (&X)[16], v2f (&Y)[16],
                                     float& dnX, float& dnY,
                                     float& sX, float& rsX,
                                     float& sY, float& rsY, bool low) {
    v2f p0 = X[0] * Y[0], p1 = X[1] * Y[1], p2 = X[2] * Y[2], p3 = X[3] * Y[3];
    #pragma unroll
    for (int j = 4; j < 16; j += 4) {
        p0 += X[j] * Y[j];         p1 += X[j + 1] * Y[j + 1];
        p2 += X[j + 2] * Y[j + 2]; p3 += X[j + 3] * Y[j + 3];
    }
    v2f pt = (p0 + p1) + (p2 + p3);
    const float raw = pt.x + pt.y;
    const float apq = (sX * sY) * raw;
    const float b   = apq + apq;
    const float d   = dnY - dnX;
    const float r2  = __builtin_fmaf(d, d, b * b);
    const float sr  = __builtin_amdgcn_sqrtf(r2);
    const float u   = fmaxf(fabsf(d) + sr, 1e-30f);
    const bool  neg = (d < 0.f) || (d == 0.f && !low);
    const float t   = (neg ? -b : b) * __builtin_amdgcn_rcpf(u);
    const float s1f = __builtin_fmaf(t, t, 1.f);
    const float c   = __builtin_amdgcn_rsqf(s1f);
    const float rc  = c * s1f;
    const float gX  = -t * (sY * rsX);
    const float gY  =  t * (sX * rsY);
    const v2f gX2 = {gX, gX}, gY2 = {gY, gY};
    #pragma unroll
    for (int j = 0; j < 16; ++j) {
        const v2f yo = Y[j];
        Y[j] = yo + gY2 * X[j];
        X[j] = X[j] + gX2 * yo;
    }
    dnX = __builtin_fmaf(-t, apq, dnX);
    dnY = __builtin_fmaf( t, apq, dnY);
    sX *= c; rsX *= rc;
    sY *= c; rsY *= rc;
}

// One tournament meeting vs group g^m (order consistent with partner:
// final two rotations are disjoint -> commute).
template<int CTRL>
__device__ __forceinline__ void meeting(v2f (&v0)[16], v2f (&v1)[16],
                                        float& dn0, float& dn1,
                                        float& s0, float& rs0,
                                        float& s1_, float& rs1, int m, int g) {
    const bool low = g < (g ^ m);
    v2f c0[16], c1[16];
    #pragma unroll
    for (int j = 0; j < 16; ++j) {
        c0[j].x = xsh<CTRL>(v0[j].x, m);
        c0[j].y = xsh<CTRL>(v0[j].y, m);
    }
    float cdn0 = xsh<CTRL>(dn0, m), cs0 = xsh<CTRL>(s0, m), crs0 = xsh<CTRL>(rs0, m);
    #pragma unroll
    for (int j = 0; j < 16; ++j) {
        c1[j].x = xsh<CTRL>(v1[j].x, m);
        c1[j].y = xsh<CTRL>(v1[j].y, m);
    }
    float cdn1 = xsh<CTRL>(dn1, m), cs1 = xsh<CTRL>(s1_, m), crs1 = xsh<CTRL>(rs1, m);
    rot2(v0, c0, dn0, cdn0, s0, rs0, cs0, crs0, low);
    rot2(v1, c1, dn1, cdn1, s1_, rs1, cs1, crs1, low);
    rot2(v0, c1, dn0, cdn1, s0, rs0, cs1, crs1, low);
    rot2(v1, c0, dn1, cdn0, s1_, rs1, cs0, crs0, low);
}

// ---------------------------------------------------------------------------
// Blocked one-sided Jacobi: lane owns cols {2g,2g+1}; 16 lanes/matrix;
// 4 matrices/wave.
// ---------------------------------------------------------------------------
__device__ __forceinline__ void jacobi_blk(v2f (&v0)[16], v2f (&v1)[16], int g,
                                           int sweeps, float& odn0, float& odn1) {
    #pragma unroll 1
    for (int sw = 0; sw < sweeps; ++sw) {
        float dn0 = nrm16(v0), dn1 = nrm16(v1);
        float s0 = 1.f, rs0 = 1.f, s1_ = 1.f, rs1 = 1.f;
        rot2(v0, v1, dn0, dn1, s0, rs0, s1_, rs1, true);  // intra pair
        meeting<0xB1>(v0, v1, dn0, dn1, s0, rs0, s1_, rs1, 1, g);
        meeting<0x4E>(v0, v1, dn0, dn1, s0, rs0, s1_, rs1, 2, g);
        meeting<0x1B>(v0, v1, dn0, dn1, s0, rs0, s1_, rs1, 3, g);
        #pragma unroll 1
        for (int m = 4; m <= 15; ++m)
            meeting<0>(v0, v1, dn0, dn1, s0, rs0, s1_, rs1, m, g);
        const v2f f0 = {s0, s0}, f1 = {s1_, s1_};
        #pragma unroll
        for (int j = 0; j < 16; ++j) { v0[j] *= f0; v1[j] *= f1; }
    }
    odn0 = nrm16(v0);
    odn1 = nrm16(v1);
}

// ---------------------------------------------------------------------------
// Single-wave 1-col Jacobi (k_small_prep / k_karcher only).
// ---------------------------------------------------------------------------
template<int CTRL>
__device__ __forceinline__ void jac_round(v2f (&v)[16], int col, int m,
                                          float& dn, float& sc, float& rsc) {
    const float dnq = xsh<CTRL>(dn, m);
    const float dq  = xsh<CTRL>(sc, m);
    v2f o[16];
    #pragma unroll
    for (int j = 0; j < 16; ++j) {
        o[j].x = xsh<CTRL>(v[j].x, m);
        o[j].y = xsh<CTRL>(v[j].y, m);
    }
    v2f p0 = v[0] * o[0], p1 = v[1] * o[1], p2 = v[2] * o[2], p3 = v[3] * o[3];
    #pragma unroll
    for (int j = 4; j < 16; j += 4) {
        p0 += v[j] * o[j];     p1 += v[j + 1] * o[j + 1];
        p2 += v[j + 2] * o[j + 2]; p3 += v[j + 3] * o[j + 3];
    }
    v2f pt = (p0 + p1) + (p2 + p3);
    const float raw = pt.x + pt.y;
    const bool  isp = col < (col ^ m);
    const float apq = (sc * dq) * raw;
    const float b   = apq + apq;
    const float d   = isp ? (dnq - dn) : (dn - dnq);
    const float r2  = __builtin_fmaf(d, d, b * b);
    const float sr  = __builtin_amdgcn_sqrtf(r2);
    const float u   = fmaxf(fabsf(d) + sr, 1e-30f);
    const float t   = (d < 0.f ? -b : b) * __builtin_amdgcn_rcpf(u);
    const float s1  = __builtin_fmaf(t, t, 1.f);
    const float c   = __builtin_amdgcn_rsqf(s1);
    const float gam = t * (dq * rsc);
    const float gs  = isp ? -gam : gam;
    const v2f gs2 = {gs, gs};
    #pragma unroll
    for (int j = 0; j < 16; ++j) v[j] += gs2 * o[j];
    sc *= c; rsc *= c * s1;
    dn = __builtin_fmaf(isp ? -t : t, apq, dn);
}

__device__ __forceinline__ float jacobi_fg(v2f (&v)[16], int col, int sweeps) {
    #pragma unroll 1
    for (int sweep = 0; sweep < sweeps; ++sweep) {
        float dn = nrm16(v);
        float sc = 1.f, rsc = 1.f;
        jac_round<0xB1>(v, col, 1, dn, sc, rsc);
        jac_round<0x4E>(v, col, 2, dn, sc, rsc);
        jac_round<0x1B>(v, col, 3, dn, sc, rsc);
        #pragma unroll 1
        for (int m = 4; m < 32; ++m) jac_round<0>(v, col, m, dn, sc, rsc);
        const v2f s2 = {sc, sc};
        #pragma unroll
        for (int j = 0; j < 16; ++j) v[j] *= s2;
    }
    return nrm16(v);
}

__device__ __forceinline__ void put_col(float* L, const v2f (&w)[16], int col) {
    #pragma unroll
    for (int j = 0; j < 16; ++j) {
        L[(2 * j) * SP + col]     = w[j].x;
        L[(2 * j + 1) * SP + col] = w[j].y;
    }
}

__device__ __forceinline__ void colmm(const float* L, const v2f (&y)[16], v2f (&z)[16]) {
    #pragma unroll
    for (int i = 0; i < 32; ++i) {
        v2f acc = {0.f, 0.f};
        #pragma unroll
        for (int q = 0; q < 16; ++q) {
            v2f mm = *(const v2f*)&L[i * SP + 2 * q];
            acc += mm * y[q];
        }
        float zi = acc.x + acc.y;
        if (i & 1) z[i >> 1].y = zi; else z[i >> 1].x = zi;
    }
}

__device__ __forceinline__ void recon_col(const float* LW, float coef, int col,
                                          int base, v2f (&z)[16]) {
    float rv[32];
    #pragma unroll
    for (int k = 0; k < 32; ++k) rv[k] = LW[col * SP + k];
    v2f y[16];
    #pragma unroll
    for (int q = 0; q < 16; ++q) {
        y[q].x = __shfl(coef, base | (2 * q), 64)     * rv[2 * q];
        y[q].y = __shfl(coef, base | (2 * q + 1), 64) * rv[2 * q + 1];
    }
    colmm(LW, y, z);
}

// ---------------------------------------------------------------------------
// K1: arithmetic mean -> ws[WS_G]
// ---------------------------------------------------------------------------
__global__ __launch_bounds__(256) void k_mean(const float* __restrict__ X,
                                              float* __restrict__ ws) {
    const int t = threadIdx.x;
    const size_t base = (size_t)blockIdx.x * 64 * 1024;
    float4 a = {0.f, 0.f, 0.f, 0.f};
    for (int m = 0; m < 64; ++m) {
        float4 f = *(const float4*)&X[base + (size_t)m * 1024 + t * 4];
        a.x += f.x; a.y += f.y; a.z += f.z; a.w += f.w;
    }
    const float s = 1.0f / (float)NMAT;
    atomicAdd(ws + WS_G + 4 * t + 0, a.x * s);
    atomicAdd(ws + WS_G + 4 * t + 1, a.y * s);
    atomicAdd(ws + WS_G + 4 * t + 2, a.z * s);
    atomicAdd(ws + WS_G + 4 * t + 3, a.w * s);
}

// ---------------------------------------------------------------------------
// K2: block 0: eig(G) -> Gs, Gis.  block 1: eig(B) -> C = B^{1/2} R.
// ---------------------------------------------------------------------------
__global__ __launch_bounds__(64) void k_small_prep(const float* __restrict__ R,
                                                   const float* __restrict__ B,
                                                   float* __restrict__ ws) {
    __shared__ float LW[32 * SP];
    const int lane = threadIdx.x;
    const int col  = lane & 31;
    const int base = lane & 32;
    if (blockIdx.x == 0) {
        v2f w[16];
        #pragma unroll
        for (int j = 0; j < 16; ++j) {
            w[j].x = ws[WS_G + (2 * j) * 32 + col];
            w[j].y = ws[WS_G + (2 * j + 1) * 32 + col];
        }
        const float dn = jacobi_fg(w, col, SW_SINGLE);
        put_col(LW, w, col);
        __syncthreads();
        const float lam = __builtin_amdgcn_sqrtf(dn);
        const float cs  = __builtin_amdgcn_sqrtf(lam) * __builtin_amdgcn_rcpf(dn);
        const float cis = __builtin_amdgcn_rsqf(lam)  * __builtin_amdgcn_rcpf(dn);
        v2f z[16];
        recon_col(LW, cs, col, base, z);
        #pragma unroll
        for (int j = 0; j < 16; ++j) {
            ws[WS_GS + (2 * j) * 32 + col]     = z[j].x;
            ws[WS_GS + (2 * j + 1) * 32 + col] = z[j].y;
        }
        recon_col(LW, cis, col, base, z);
        #pragma unroll
        for (int j = 0; j < 16; ++j) {
            ws[WS_GIS + (2 * j) * 32 + col]     = z[j].x;
            ws[WS_GIS + (2 * j + 1) * 32 + col] = z[j].y;
        }
    } else {
        v2f w[16];
        #pragma unroll
        for (int j = 0; j < 16; ++j) {
            w[j].x = B[(2 * j) * 32 + col];
            w[j].y = B[(2 * j + 1) * 32 + col];
        }
        const float dn = jacobi_fg(w, col, SW_SINGLE);
        put_col(LW, w, col);
        __syncthreads();
        const float lam = __builtin_amdgcn_sqrtf(dn);
        const float cbs = __builtin_amdgcn_sqrtf(lam) * __builtin_amdgcn_rcpf(dn);
        v2f bs[16];
        recon_col(LW, cbs, col, base, bs);
        __syncthreads();
        put_col(LW, bs, col);
        __syncthreads();
        v2f r[16];
        #pragma unroll
        for (int j = 0; j < 16; ++j) {
            r[j].x = R[(2 * j) * 32 + col];
            r[j].y = R[(2 * j + 1) * 32 + col];
        }
        v2f c[16];
        colmm(LW, r, c);
        #pragma unroll
        for (int j = 0; j < 16; ++j) {
            ws[WS_C + (2 * j) * 32 + col]     = c[j].x;
            ws[WS_C + (2 * j + 1) * 32 + col] = c[j].y;
        }
    }
}

// ---------------------------------------------------------------------------
// K3 (pass 1): M = Gis X Gis; blocked Jacobi (4 mat/wave); W1 -> w1out;
// GT/S1/S2 accumulation. No min-occupancy clamp: needs ~160 VGPR, no spill.
// ---------------------------------------------------------------------------
__global__ __launch_bounds__(256) void k_batch_log(const float* __restrict__ X,
                                                   float* __restrict__ w1out,
                                                   float* __restrict__ ws) {
    __shared__ float HL[1024];       // Gis, pair-swizzled
    __shared__ float TW[4][1024];    // per-wave take-turns W tile
    __shared__ float GB[4][4][32];   // per-wave, per-stage g coefficients
    __shared__ float ACC[1024];
    __shared__ float S1B, S2B;
    const int tid = threadIdx.x;
    if (tid == 0) { S1B = 0.f; S2B = 0.f; }
    for (int e = tid; e < 1024; e += 256) {
        int r = e >> 5, c = e & 31;
        HL[swz(r, c)] = ws[WS_GIS + e];
        ACC[e] = 0.f;
    }
    __syncthreads();

    const int lane = tid & 63;
    const int wv   = tid >> 6;
    const int q    = lane >> 4;          // matrix quarter within wave
    const int g    = lane & 15;          // group (owns cols 2g, 2g+1)
    const int c0   = 2 * g;
    const size_t gm = (size_t)blockIdx.x * 16 + wv * 4 + q;
    const float* Xm = X + gm * 1024;
    float* tw = TW[wv];

    v2f v0[16], v1[16];
    {   // congruence temporaries scoped: registers retire before Jacobi
        v2f h0[16], h1[16];
        const int e0 = c0 & 15, e1 = (c0 + 1) & 15;
        #pragma unroll
        for (int p = 0; p < 16; ++p) {
            h0[p] = *(const v2f*)&HL[c0 * 32 + 2 * (p ^ e0)];
            h1[p] = *(const v2f*)&HL[(c0 + 1) * 32 + 2 * (p ^ e1)];
        }
        v2f t0[16], t1[16];
        #pragma unroll
        for (int i = 0; i < 32; ++i) {
            const float4* row = (const float4*)(Xm + i * 32);
            v2f a0 = {0.f, 0.f}, a1 = {0.f, 0.f};
            #pragma unroll
            for (int q8 = 0; q8 < 8; ++q8) {
                float4 f = row[q8];
                v2f lo = {f.x, f.y}, hi = {f.z, f.w};
                a0 += lo * h0[2 * q8] + hi * h0[2 * q8 + 1];
                a1 += lo * h1[2 * q8] + hi * h1[2 * q8 + 1];
            }
            float u0 = a0.x + a0.y, u1 = a1.x + a1.y;
            if (i & 1) { t0[i >> 1].y = u0; t1[i >> 1].y = u1; }
            else       { t0[i >> 1].x = u0; t1[i >> 1].x = u1; }
        }
        #pragma unroll
        for (int i = 0; i < 32; ++i) {
            const int twi = i & 15;
            v2f a0 = {0.f, 0.f}, a1 = {0.f, 0.f};
            #pragma unroll
            for (int q8 = 0; q8 < 8; ++q8) {
                v4f f = *(const v4f*)&HL[i * 32 + 4 * q8];
                v2f lo = {f.x, f.y}, hi = {f.z, f.w};
                a0 += lo * t0[(2 * q8) ^ twi] + hi * t0[(2 * q8 + 1) ^ twi];
                a1 += lo * t1[(2 * q8) ^ twi] + hi * t1[(2 * q8 + 1) ^ twi];
            }
            float u0 = a0.x + a0.y, u1 = a1.x + a1.y;
            if (i & 1) { v0[i >> 1].y = u0; v1[i >> 1].y = u1; }
            else       { v0[i >> 1].x = u0; v1[i >> 1].x = u1; }
        }
    }

    float dn0, dn1;
    jacobi_blk(v0, v1, g, SW1, dn0, dn1);

    // W1 -> global (row-pair v2f stores)
    float* op = w1out + gm * 1024 + c0;
    #pragma unroll
    for (int j = 0; j < 16; ++j) {
        *(v2f*)&op[(2 * j) * 32]     = mk2(v0[j].x, v1[j].x);
        *(v2f*)&op[(2 * j + 1) * 32] = mk2(v0[j].y, v1[j].y);
    }

    // log-eigen stats
    const float ls0 = 0.5f * logf(dn0), ls1 = 0.5f * logf(dn1);
    const float invN = 1.0f / (float)NMAT;
    const float g0 = ls0 * __builtin_amdgcn_rcpf(dn0) * invN;
    const float g1 = ls1 * __builtin_amdgcn_rcpf(dn1) * invN;
    {
        float s1v = ls0 + ls1, s2v = ls0 * ls0 + ls1 * ls1;
        #pragma unroll
        for (int m = 32; m >= 1; m >>= 1) {
            s1v += __shfl_xor(s1v, m, 64);
            s2v += __shfl_xor(s2v, m, 64);
        }
        if (lane == 0) { atomicAdd(&S1B, s1v); atomicAdd(&S2B, s2v); }
    }

    // GT recon: 4-stage take-turns tile per wave
    float accR[16];
    #pragma unroll
    for (int i = 0; i < 16; ++i) accR[i] = 0.f;
    const int cc = lane & 31, half = lane >> 5;
    const int cm = cc & 15, cbase = cc * 32;

    #pragma unroll 1
    for (int s = 0; s < 4; ++s) {
        if (q == s) {
            #pragma unroll
            for (int j = 0; j < 16; ++j) {
                *(v2f*)&tw[(2 * j) * 32 + 2 * (g ^ ((2 * j) & 15))]         = mk2(v0[j].x, v1[j].x);
                *(v2f*)&tw[(2 * j + 1) * 32 + 2 * (g ^ ((2 * j + 1) & 15))] = mk2(v0[j].y, v1[j].y);
            }
            *(v2f*)&GB[wv][s][c0] = mk2(g0, g1);
        }
        wave_fence();
        v2f gr[16];
        #pragma unroll
        for (int p2 = 0; p2 < 16; ++p2) {
            v2f wr = *(const v2f*)&tw[cbase + 2 * (p2 ^ cm)];
            v2f gg = *(const v2f*)&GB[wv][s][2 * p2];
            gr[p2] = gg * wr;
        }
        #pragma unroll
        for (int i = 0; i < 16; ++i) {
            const int r = half * 16 + i;
            const int rw = r & 15;
            v2f acc = {0.f, 0.f};
            #pragma unroll
            for (int q8 = 0; q8 < 8; ++q8) {
                v4f f = *(const v4f*)&tw[r * 32 + 4 * q8];
                v2f lo = {f.x, f.y}, hi = {f.z, f.w};
                acc += lo * gr[(2 * q8) ^ rw] + hi * gr[(2 * q8 + 1) ^ rw];
            }
            accR[i] += acc.x + acc.y;
        }
        wave_fence();
    }
    #pragma unroll
    for (int i = 0; i < 16; ++i)
        atomicAdd(&ACC[(half * 16 + i) * 32 + cc], accR[i]);
    __syncthreads();
    for (int e = tid; e < 1024; e += 256) atomicAdd(ws + WS_GT + e, ACC[e]);
    if (tid == 0) {
        atomicAdd(ws + WS_S1, S1B * invN);
        atomicAdd(ws + WS_S2, S2B * invN);
    }
}

// ---------------------------------------------------------------------------
// K4: E = exp(GT); Gn = Gs E Gs; Gh = Gn^{-1/2}; K = Gh*Gs; p from S1,S2.
// ---------------------------------------------------------------------------
__global__ __launch_bounds__(64) void k_karcher(float* __restrict__ ws) {
    __shared__ float LA[32 * SP];
    __shared__ float LB[32 * SP];
    const int lane = threadIdx.x;
    const int col  = lane & 31;
    const int base = lane & 32;

    for (int e = lane; e < 1024; e += 64)
        LB[(e >> 5) * SP + (e & 31)] = ws[WS_GS + e];
    v2f gsc[16];
    #pragma unroll
    for (int j = 0; j < 16; ++j) {
        gsc[j].x = ws[WS_GS + (2 * j) * 32 + col];
        gsc[j].y = ws[WS_GS + (2 * j + 1) * 32 + col];
    }
    v2f w[16];
    #pragma unroll
    for (int j = 0; j < 16; ++j) {
        w[j].x = ws[WS_GT + (2 * j) * 32 + col];
        w[j].y = ws[WS_GT + (2 * j + 1) * 32 + col];
    }
    v2f cn2 = {0.f, 0.f};
    #pragma unroll
    for (int j = 0; j < 16; ++j) cn2 += w[j] * w[j];
    float fro2 = cn2.x + cn2.y;
    #pragma unroll
    for (int m = 16; m >= 1; m >>= 1) fro2 += __shfl_xor(fro2, m, 64);
    const float shift = __builtin_amdgcn_sqrtf(fro2) + 0.01f;
    #pragma unroll
    for (int j = 0; j < 16; ++j) {
        w[j].x += (2 * j     == col) ? shift : 0.f;
        w[j].y += (2 * j + 1 == col) ? shift : 0.f;
    }
    const float dn = jacobi_fg(w, col, SW_SINGLE);
    put_col(LA, w, col);
    __syncthreads();
    const float lam = __builtin_amdgcn_sqrtf(dn) - shift;
    const float ce  = expf(lam) * __builtin_amdgcn_rcpf(dn);
    v2f ec[16];
    recon_col(LA, ce, col, base, ec);
    __syncthreads();
    put_col(LA, ec, col);
    __syncthreads();
    v2f u[16], gn[16];
    colmm(LA, gsc, u);
    colmm(LB, u, gn);
    const float dn2 = jacobi_fg(gn, col, SW_SINGLE);
    __syncthreads();
    put_col(LA, gn, col);
    __syncthreads();
    const float lam2 = __builtin_amdgcn_sqrtf(dn2);
    const float ch   = __builtin_amdgcn_rsqf(lam2) * __builtin_amdgcn_rcpf(dn2);
    v2f gh[16];
    recon_col(LA, ch, col, base, gh);
    __syncthreads();
    put_col(LA, gh, col);
    __syncthreads();
    v2f kc[16];
    colmm(LA, gsc, kc);
    #pragma unroll
    for (int j = 0; j < 16; ++j) {
        ws[WS_K + (2 * j) * 32 + col]     = kc[j].x;
        ws[WS_K + (2 * j + 1) * 32 + col] = kc[j].y;
    }
    if (lane == 0) {
        const float S1  = ws[WS_S1];
        const float S2  = ws[WS_S2];
        const float var = S2 - S1 * S1 * 0.03125f;
        ws[WS_P] = __builtin_amdgcn_rsqf(var + 1e-5f);
    }
}

// ---------------------------------------------------------------------------
// K5 (fused warm+final): F = K W1 diag(lam1^{-1/2}); blocked Jacobi;
// Y = C W2 diag(lam^{(p-1)/2}); out = Y Y^T (4-stage take-turns tile).
// ---------------------------------------------------------------------------
__global__ __launch_bounds__(256) void k_fused(float* __restrict__ out,
                                               const float* __restrict__ ws) {
    __shared__ float KL[1024];
    __shared__ float CL[1024];
    __shared__ float TW[4][1024];
    const int tid = threadIdx.x;
    for (int e = tid; e < 1024; e += 256) {
        KL[e] = ws[WS_K + e];
        CL[e] = ws[WS_C + e];
    }
    __syncthreads();

    const int lane = tid & 63;
    const int wv   = tid >> 6;
    const int q    = lane >> 4;
    const int g    = lane & 15;
    const int c0   = 2 * g;
    const size_t gmbase = (size_t)blockIdx.x * 16 + wv * 4;
    const size_t gm = gmbase + q;
    float* tw = TW[wv];
    const float p = ws[WS_P];

    v2f v0[16], v1[16];
    {   // load + scale + K-multiply scoped
        const float* wp = out + gm * 1024 + c0;
        v2f t0[16], t1[16];
        #pragma unroll
        for (int j = 0; j < 16; ++j) {
            v2f la = *(const v2f*)&wp[(2 * j) * 32];
            v2f lb = *(const v2f*)&wp[(2 * j + 1) * 32];
            t0[j] = mk2(la.x, lb.x);
            t1[j] = mk2(la.y, lb.y);
        }
        const float nn0 = nrm16(t0), nn1 = nrm16(t1);
        const float sc0 = __builtin_amdgcn_rsqf(__builtin_amdgcn_sqrtf(nn0));
        const float sc1 = __builtin_amdgcn_rsqf(__builtin_amdgcn_sqrtf(nn1));
        const v2f sv0 = {sc0, sc0}, sv1 = {sc1, sc1};
        #pragma unroll
        for (int j = 0; j < 16; ++j) { t0[j] *= sv0; t1[j] *= sv1; }
        #pragma unroll
        for (int i = 0; i < 32; ++i) {
            v2f a0 = {0.f, 0.f}, a1 = {0.f, 0.f};
            #pragma unroll
            for (int q8 = 0; q8 < 8; ++q8) {
                v4f f = *(const v4f*)&KL[i * 32 + 4 * q8];
                v2f lo = {f.x, f.y}, hi = {f.z, f.w};
                a0 += lo * t0[2 * q8] + hi * t0[2 * q8 + 1];
                a1 += lo * t1[2 * q8] + hi * t1[2 * q8 + 1];
            }
            float u0 = a0.x + a0.y, u1 = a1.x + a1.y;
            if (i & 1) { v0[i >> 1].y = u0; v1[i >> 1].y = u1; }
            else       { v0[i >> 1].x = u0; v1[i >> 1].x = u1; }
        }
    }

    float dn0, dn1;
    jacobi_blk(v0, v1, g, SW2, dn0, dn1);   // dn = lambda (factor form)

    const float dj0 = exp2f(log2f(dn0) * 0.5f * (p - 1.0f));
    const float dj1 = exp2f(log2f(dn1) * 0.5f * (p - 1.0f));
    const v2f dv0 = {dj0, dj0}, dv1 = {dj1, dj1};
    v2f y0[16], y1[16];
    {
        v2f t0[16], t1[16];
        #pragma unroll
        for (int j = 0; j < 16; ++j) { t0[j] = v0[j] * dv0; t1[j] = v1[j] * dv1; }
        #pragma unroll
        for (int i = 0; i < 32; ++i) {
            v2f a0 = {0.f, 0.f}, a1 = {0.f, 0.f};
            #pragma unroll
            for (int q8 = 0; q8 < 8; ++q8) {
                v4f f = *(const v4f*)&CL[i * 32 + 4 * q8];
                v2f lo = {f.x, f.y}, hi = {f.z, f.w};
                a0 += lo * t0[2 * q8] + hi * t0[2 * q8 + 1];
                a1 += lo * t1[2 * q8] + hi * t1[2 * q8 + 1];
            }
            float u0 = a0.x + a0.y, u1 = a1.x + a1.y;
            if (i & 1) { y0[i >> 1].y = u0; y1[i >> 1].y = u1; }
            else       { y0[i >> 1].x = u0; y1[i >> 1].x = u1; }
        }
    }

    // out = Y Y^T, 4-stage take-turns tile
    const int cc = lane & 31, half = lane >> 5;
    const int cm = cc & 15, cbase = cc * 32;
    #pragma unroll 1
    for (int s = 0; s < 4; ++s) {
        if (q == s) {
            #pragma unroll
            for (int j = 0; j < 16; ++j) {
                *(v2f*)&tw[(2 * j) * 32 + 2 * (g ^ ((2 * j) & 15))]         = mk2(y0[j].x, y1[j].x);
                *(v2f*)&tw[(2 * j + 1) * 32 + 2 * (g ^ ((2 * j + 1) & 15))] = mk2(y0[j].y, y1[j].y);
            }
        }
        wave_fence();
        v2f yc[16];
        #pragma unroll
        for (int p2 = 0; p2 < 16; ++p2)
            yc[p2] = *(const v2f*)&tw[cbase + 2 * (p2 ^ cm)];
        const size_t gmo = gmbase + s;
        #pragma unroll
        for (int i = 0; i < 16; ++i) {
            const int r = half * 16 + i;
            const int rw = r & 15;
            v2f acc = {0.f, 0.f};
            #pragma unroll
            for (int q8 = 0; q8 < 8; ++q8) {
                v4f f = *(const v4f*)&tw[r * 32 + 4 * q8];
                v2f lo = {f.x, f.y}, hi = {f.z, f.w};
                acc += lo * yc[(2 * q8) ^ rw] + hi * yc[(2 * q8 + 1) ^ rw];
            }
            out[gmo * 1024 + r * 32 + cc] = acc.x + acc.y;
        }
        wave_fence();
    }
}

extern "C" void kernel_launch(void* const* d_in, const int* in_sizes, int n_in,
                              void* d_out, int out_size, void* d_ws, size_t ws_size,
                              hipStream_t stream) {
    const float* X = (const float*)d_in[0];
    const float* R = (const float*)d_in[1];
    const float* B = (const float*)d_in[2];
    float* out = (float*)d_out;
    float* ws  = (float*)d_ws;

    hipMemsetAsync(d_ws, 0, WS_TOTAL * sizeof(float), stream);
    k_mean<<<NMAT / 64, 256, 0, stream>>>(X, ws);
    k_small_prep<<<2, 64, 0, stream>>>(R, B, ws);
    k_batch_log<<<NMAT / 16, 256, 0, stream>>>(X, out, ws);
    k_karcher<<<1, 64, 0, stream>>>(ws);
    k_fused<<<NMAT / 16, 256, 0, stream>>>(out, ws);
}

// Round 11
// 1725.622 us; speedup vs baseline: 2.7486x; 1.0214x over previous
//
#include <hip/hip_runtime.h>
#include <math.h>

typedef float v2f __attribute__((ext_vector_type(2)));
typedef float v4f __attribute__((ext_vector_type(4)));

#define NMAT 32768
#define SW1 4          // pass-1 sweeps (r7 passed at 4; r8 failure was DPP mirrors)
#define SW2 2          // pass-2 sweeps (warm start; quadratic)
#define SW_SINGLE 10   // single-matrix eigs
#define SP 34          // padded row stride for single-wave LDS matrices

// workspace float offsets
#define WS_G    0
#define WS_GS   1024
#define WS_GIS  2048
#define WS_GT   3072
#define WS_K    4096
#define WS_C    5120
#define WS_S1   6144
#define WS_S2   6145
#define WS_P    6146
#define WS_TOTAL 6400

__device__ __forceinline__ int swz(int r, int c) {
    return r * 32 + 2 * ((c >> 1) ^ (r & 15)) + (c & 1);
}
__device__ __forceinline__ void wave_fence() {
    asm volatile("s_waitcnt lgkmcnt(0)" ::: "memory");
}
__device__ __forceinline__ v2f mk2(float a, float b) { v2f r; r.x = a; r.y = b; return r; }

// xor-shuffle: CTRL!=0 -> VALU DPP quad_perm (masks 1,2,3 ONLY — row mirrors
// 0x140/0x141 are broken on this path, r8 evidence); CTRL==0 -> DS.
template<int CTRL>
__device__ __forceinline__ float xsh(float x, int m) {
    if constexpr (CTRL != 0) {
        return __int_as_float(__builtin_amdgcn_update_dpp(
            __float_as_int(x), __float_as_int(x), CTRL, 0xF, 0xF, true));
    } else {
        return __shfl_xor(x, m, 64);
    }
}

__device__ __forceinline__ float nrm16(const v2f (&v)[16]) {
    v2f n0 = v[0] * v[0], n1 = v[1] * v[1], n2 = v[2] * v[2], n3 = v[3] * v[3];
    #pragma unroll
    for (int j = 4; j < 16; j += 4) {
        n0 += v[j] * v[j];     n1 += v[j + 1] * v[j + 1];
        n2 += v[j + 2] * v[j + 2]; n3 += v[j + 3] * v[j + 3];
    }
    v2f nt = (n0 + n1) + (n2 + n3);
    return nt.x + nt.y;
}

// ---------------------------------------------------------------------------
// Symmetric fast-Givens rotation on column pair (X,Y); deterministic d==0
// tie-break via `low`.
// ---------------------------------------------------------------------------
__device__ __forceinline__ void rot2(v2f (&X)[16], v2f (&Y)[16],
                                     float& dnX, float& dnY,
                                     float& sX, float& rsX,
                                     float& sY, float& rsY, bool low) {
    v2f p0 = X[0] * Y[0], p1 = X[1] * Y[1], p2 = X[2] * Y[2], p3 = X[3] * Y[3];
    #pragma unroll
    for (int j = 4; j < 16; j += 4) {
        p0 += X[j] * Y[j];         p1 += X[j + 1] * Y[j + 1];
        p2 += X[j + 2] * Y[j + 2]; p3 += X[j + 3] * Y[j + 3];
    }
    v2f pt = (p0 + p1) + (p2 + p3);
    const float raw = pt.x + pt.y;
    const float apq = (sX * sY) * raw;
    const float b   = apq + apq;
    const float d   = dnY - dnX;
    const float r2  = __builtin_fmaf(d, d, b * b);
    const float sr  = __builtin_amdgcn_sqrtf(r2);
    const float u   = fmaxf(fabsf(d) + sr, 1e-30f);
    const bool  neg = (d < 0.f) || (d == 0.f && !low);
    const float t   = (neg ? -b : b) * __builtin_amdgcn_rcpf(u);
    const float s1f = __builtin_fmaf(t, t, 1.f);
    const float c   = __builtin_amdgcn_rsqf(s1f);
    const float rc  = c * s1f;
    const float gX  = -t * (sY * rsX);
    const float gY  =  t * (sX * rsY);
    const v2f gX2 = {gX, gX}, gY2 = {gY, gY};
    #pragma unroll
    for (int j = 0; j < 16; ++j) {
        const v2f yo = Y[j];
        Y[j] = yo + gY2 * X[j];
        X[j] = X[j] + gX2 * yo;
    }
    dnX = __builtin_fmaf(-t, apq, dnX);
    dnY = __builtin_fmaf( t, apq, dnY);
    sX *= c; rsX *= rc;
    sY *= c; rsY *= rc;
}

// One tournament meeting vs group g^m.
template<int CTRL>
__device__ __forceinline__ void meeting(v2f (&v0)[16], v2f (&v1)[16],
                                        float& dn0, float& dn1,
                                        float& s0, float& rs0,
                                        float& s1_, float& rs1, int m, int g) {
    const bool low = g < (g ^ m);
    v2f c0[16], c1[16];
    #pragma unroll
    for (int j = 0; j < 16; ++j) {
        c0[j].x = xsh<CTRL>(v0[j].x, m);
        c0[j].y = xsh<CTRL>(v0[j].y, m);
    }
    float cdn0 = xsh<CTRL>(dn0, m), cs0 = xsh<CTRL>(s0, m), crs0 = xsh<CTRL>(rs0, m);
    #pragma unroll
    for (int j = 0; j < 16; ++j) {
        c1[j].x = xsh<CTRL>(v1[j].x, m);
        c1[j].y = xsh<CTRL>(v1[j].y, m);
    }
    float cdn1 = xsh<CTRL>(dn1, m), cs1 = xsh<CTRL>(s1_, m), crs1 = xsh<CTRL>(rs1, m);
    rot2(v0, c0, dn0, cdn0, s0, rs0, cs0, crs0, low);
    rot2(v1, c1, dn1, cdn1, s1_, rs1, cs1, crs1, low);
    rot2(v0, c1, dn0, cdn1, s0, rs0, cs1, crs1, low);
    rot2(v1, c0, dn1, cdn0, s1_, rs1, cs0, crs0, low);
}

// ---------------------------------------------------------------------------
// Blocked one-sided Jacobi: lane owns cols {2g,2g+1}; 16 lanes/matrix;
// 4 matrices/wave.
// ---------------------------------------------------------------------------
__device__ __forceinline__ void jacobi_blk(v2f (&v0)[16], v2f (&v1)[16], int g,
                                           int sweeps, float& odn0, float& odn1) {
    #pragma unroll 1
    for (int sw = 0; sw < sweeps; ++sw) {
        float dn0 = nrm16(v0), dn1 = nrm16(v1);
        float s0 = 1.f, rs0 = 1.f, s1_ = 1.f, rs1 = 1.f;
        rot2(v0, v1, dn0, dn1, s0, rs0, s1_, rs1, true);  // intra pair
        meeting<0xB1>(v0, v1, dn0, dn1, s0, rs0, s1_, rs1, 1, g);
        meeting<0x4E>(v0, v1, dn0, dn1, s0, rs0, s1_, rs1, 2, g);
        meeting<0x1B>(v0, v1, dn0, dn1, s0, rs0, s1_, rs1, 3, g);
        #pragma unroll 1
        for (int m = 4; m <= 15; ++m)
            meeting<0>(v0, v1, dn0, dn1, s0, rs0, s1_, rs1, m, g);
        const v2f f0 = {s0, s0}, f1 = {s1_, s1_};
        #pragma unroll
        for (int j = 0; j < 16; ++j) { v0[j] *= f0; v1[j] *= f1; }
    }
    odn0 = nrm16(v0);
    odn1 = nrm16(v1);
}

// ---------------------------------------------------------------------------
// Single-wave 1-col Jacobi (k_small_prep / k_karcher only).
// ---------------------------------------------------------------------------
template<int CTRL>
__device__ __forceinline__ void jac_round(v2f (&v)[16], int col, int m,
                                          float& dn, float& sc, float& rsc) {
    const float dnq = xsh<CTRL>(dn, m);
    const float dq  = xsh<CTRL>(sc, m);
    v2f o[16];
    #pragma unroll
    for (int j = 0; j < 16; ++j) {
        o[j].x = xsh<CTRL>(v[j].x, m);
        o[j].y = xsh<CTRL>(v[j].y, m);
    }
    v2f p0 = v[0] * o[0], p1 = v[1] * o[1], p2 = v[2] * o[2], p3 = v[3] * o[3];
    #pragma unroll
    for (int j = 4; j < 16; j += 4) {
        p0 += v[j] * o[j];     p1 += v[j + 1] * o[j + 1];
        p2 += v[j + 2] * o[j + 2]; p3 += v[j + 3] * o[j + 3];
    }
    v2f pt = (p0 + p1) + (p2 + p3);
    const float raw = pt.x + pt.y;
    const bool  isp = col < (col ^ m);
    const float apq = (sc * dq) * raw;
    const float b   = apq + apq;
    const float d   = isp ? (dnq - dn) : (dn - dnq);
    const float r2  = __builtin_fmaf(d, d, b * b);
    const float sr  = __builtin_amdgcn_sqrtf(r2);
    const float u   = fmaxf(fabsf(d) + sr, 1e-30f);
    const float t   = (d < 0.f ? -b : b) * __builtin_amdgcn_rcpf(u);
    const float s1  = __builtin_fmaf(t, t, 1.f);
    const float c   = __builtin_amdgcn_rsqf(s1);
    const float gam = t * (dq * rsc);
    const float gs  = isp ? -gam : gam;
    const v2f gs2 = {gs, gs};
    #pragma unroll
    for (int j = 0; j < 16; ++j) v[j] += gs2 * o[j];
    sc *= c; rsc *= c * s1;
    dn = __builtin_fmaf(isp ? -t : t, apq, dn);
}

__device__ __forceinline__ float jacobi_fg(v2f (&v)[16], int col, int sweeps) {
    #pragma unroll 1
    for (int sweep = 0; sweep < sweeps; ++sweep) {
        float dn = nrm16(v);
        float sc = 1.f, rsc = 1.f;
        jac_round<0xB1>(v, col, 1, dn, sc, rsc);
        jac_round<0x4E>(v, col, 2, dn, sc, rsc);
        jac_round<0x1B>(v, col, 3, dn, sc, rsc);
        #pragma unroll 1
        for (int m = 4; m < 32; ++m) jac_round<0>(v, col, m, dn, sc, rsc);
        const v2f s2 = {sc, sc};
        #pragma unroll
        for (int j = 0; j < 16; ++j) v[j] *= s2;
    }
    return nrm16(v);
}

__device__ __forceinline__ void put_col(float* L, const v2f (&w)[16], int col) {
    #pragma unroll
    for (int j = 0; j < 16; ++j) {
        L[(2 * j) * SP + col]     = w[j].x;
        L[(2 * j + 1) * SP + col] = w[j].y;
    }
}

__device__ __forceinline__ void colmm(const float* L, const v2f (&y)[16], v2f (&z)[16]) {
    #pragma unroll
    for (int i = 0; i < 32; ++i) {
        v2f acc = {0.f, 0.f};
        #pragma unroll
        for (int q = 0; q < 16; ++q) {
            v2f mm = *(const v2f*)&L[i * SP + 2 * q];
            acc += mm * y[q];
        }
        float zi = acc.x + acc.y;
        if (i & 1) z[i >> 1].y = zi; else z[i >> 1].x = zi;
    }
}

__device__ __forceinline__ void recon_col(const float* LW, float coef, int col,
                                          int base, v2f (&z)[16]) {
    float rv[32];
    #pragma unroll
    for (int k = 0; k < 32; ++k) rv[k] = LW[col * SP + k];
    v2f y[16];
    #pragma unroll
    for (int q = 0; q < 16; ++q) {
        y[q].x = __shfl(coef, base | (2 * q), 64)     * rv[2 * q];
        y[q].y = __shfl(coef, base | (2 * q + 1), 64) * rv[2 * q + 1];
    }
    colmm(LW, y, z);
}

// ---------------------------------------------------------------------------
// K1: arithmetic mean -> ws[WS_G]  (2048 blocks: latency-bound at 512)
// ---------------------------------------------------------------------------
__global__ __launch_bounds__(256) void k_mean(const float* __restrict__ X,
                                              float* __restrict__ ws) {
    const int t = threadIdx.x;
    const size_t base = (size_t)blockIdx.x * 16 * 1024;
    float4 a = {0.f, 0.f, 0.f, 0.f};
    for (int m = 0; m < 16; ++m) {
        float4 f = *(const float4*)&X[base + (size_t)m * 1024 + t * 4];
        a.x += f.x; a.y += f.y; a.z += f.z; a.w += f.w;
    }
    const float s = 1.0f / (float)NMAT;
    atomicAdd(ws + WS_G + 4 * t + 0, a.x * s);
    atomicAdd(ws + WS_G + 4 * t + 1, a.y * s);
    atomicAdd(ws + WS_G + 4 * t + 2, a.z * s);
    atomicAdd(ws + WS_G + 4 * t + 3, a.w * s);
}

// ---------------------------------------------------------------------------
// K2: block 0: eig(G) -> Gs, Gis.  block 1: eig(B) -> C = B^{1/2} R.
// ---------------------------------------------------------------------------
__global__ __launch_bounds__(64) void k_small_prep(const float* __restrict__ R,
                                                   const float* __restrict__ B,
                                                   float* __restrict__ ws) {
    __shared__ float LW[32 * SP];
    const int lane = threadIdx.x;
    const int col  = lane & 31;
    const int base = lane & 32;
    if (blockIdx.x == 0) {
        v2f w[16];
        #pragma unroll
        for (int j = 0; j < 16; ++j) {
            w[j].x = ws[WS_G + (2 * j) * 32 + col];
            w[j].y = ws[WS_G + (2 * j + 1) * 32 + col];
        }
        const float dn = jacobi_fg(w, col, SW_SINGLE);
        put_col(LW, w, col);
        __syncthreads();
        const float lam = __builtin_amdgcn_sqrtf(dn);
        const float cs  = __builtin_amdgcn_sqrtf(lam) * __builtin_amdgcn_rcpf(dn);
        const float cis = __builtin_amdgcn_rsqf(lam)  * __builtin_amdgcn_rcpf(dn);
        v2f z[16];
        recon_col(LW, cs, col, base, z);
        #pragma unroll
        for (int j = 0; j < 16; ++j) {
            ws[WS_GS + (2 * j) * 32 + col]     = z[j].x;
            ws[WS_GS + (2 * j + 1) * 32 + col] = z[j].y;
        }
        recon_col(LW, cis, col, base, z);
        #pragma unroll
        for (int j = 0; j < 16; ++j) {
            ws[WS_GIS + (2 * j) * 32 + col]     = z[j].x;
            ws[WS_GIS + (2 * j + 1) * 32 + col] = z[j].y;
        }
    } else {
        v2f w[16];
        #pragma unroll
        for (int j = 0; j < 16; ++j) {
            w[j].x = B[(2 * j) * 32 + col];
            w[j].y = B[(2 * j + 1) * 32 + col];
        }
        const float dn = jacobi_fg(w, col, SW_SINGLE);
        put_col(LW, w, col);
        __syncthreads();
        const float lam = __builtin_amdgcn_sqrtf(dn);
        const float cbs = __builtin_amdgcn_sqrtf(lam) * __builtin_amdgcn_rcpf(dn);
        v2f bs[16];
        recon_col(LW, cbs, col, base, bs);
        __syncthreads();
        put_col(LW, bs, col);
        __syncthreads();
        v2f r[16];
        #pragma unroll
        for (int j = 0; j < 16; ++j) {
            r[j].x = R[(2 * j) * 32 + col];
            r[j].y = R[(2 * j + 1) * 32 + col];
        }
        v2f c[16];
        colmm(LW, r, c);
        #pragma unroll
        for (int j = 0; j < 16; ++j) {
            ws[WS_C + (2 * j) * 32 + col]     = c[j].x;
            ws[WS_C + (2 * j + 1) * 32 + col] = c[j].y;
        }
    }
}

// ---------------------------------------------------------------------------
// K3 (pass 1): M = Gis X Gis; blocked Jacobi (4 mat/wave); W1 -> w1out;
// GT/S1/S2 accumulation.
// ---------------------------------------------------------------------------
__global__ __launch_bounds__(256) void k_batch_log(const float* __restrict__ X,
                                                   float* __restrict__ w1out,
                                                   float* __restrict__ ws) {
    __shared__ float HL[1024];       // Gis, pair-swizzled
    __shared__ float TW[4][1024];    // per-wave take-turns W tile
    __shared__ float GB[4][4][32];   // per-wave, per-stage g coefficients
    __shared__ float ACC[1024];
    __shared__ float S1B, S2B;
    const int tid = threadIdx.x;
    if (tid == 0) { S1B = 0.f; S2B = 0.f; }
    for (int e = tid; e < 1024; e += 256) {
        int r = e >> 5, c = e & 31;
        HL[swz(r, c)] = ws[WS_GIS + e];
        ACC[e] = 0.f;
    }
    __syncthreads();

    const int lane = tid & 63;
    const int wv   = tid >> 6;
    const int q    = lane >> 4;          // matrix quarter within wave
    const int g    = lane & 15;          // group (owns cols 2g, 2g+1)
    const int c0   = 2 * g;
    const size_t gm = (size_t)blockIdx.x * 16 + wv * 4 + q;
    const float* Xm = X + gm * 1024;
    float* tw = TW[wv];

    v2f v0[16], v1[16];
    {   // congruence temporaries scoped: registers retire before Jacobi
        v2f h0[16], h1[16];
        const int e0 = c0 & 15, e1 = (c0 + 1) & 15;
        #pragma unroll
        for (int p = 0; p < 16; ++p) {
            h0[p] = *(const v2f*)&HL[c0 * 32 + 2 * (p ^ e0)];
            h1[p] = *(const v2f*)&HL[(c0 + 1) * 32 + 2 * (p ^ e1)];
        }
        v2f t0[16], t1[16];
        #pragma unroll
        for (int i = 0; i < 32; ++i) {
            const float4* row = (const float4*)(Xm + i * 32);
            v2f a0 = {0.f, 0.f}, a1 = {0.f, 0.f};
            #pragma unroll
            for (int q8 = 0; q8 < 8; ++q8) {
                float4 f = row[q8];
                v2f lo = {f.x, f.y}, hi = {f.z, f.w};
                a0 += lo * h0[2 * q8] + hi * h0[2 * q8 + 1];
                a1 += lo * h1[2 * q8] + hi * h1[2 * q8 + 1];
            }
            float u0 = a0.x + a0.y, u1 = a1.x + a1.y;
            if (i & 1) { t0[i >> 1].y = u0; t1[i >> 1].y = u1; }
            else       { t0[i >> 1].x = u0; t1[i >> 1].x = u1; }
        }
        #pragma unroll
        for (int i = 0; i < 32; ++i) {
            const int twi = i & 15;
            v2f a0 = {0.f, 0.f}, a1 = {0.f, 0.f};
            #pragma unroll
            for (int q8 = 0; q8 < 8; ++q8) {
                v4f f = *(const v4f*)&HL[i * 32 + 4 * q8];
                v2f lo = {f.x, f.y}, hi = {f.z, f.w};
                a0 += lo * t0[(2 * q8) ^ twi] + hi * t0[(2 * q8 + 1) ^ twi];
                a1 += lo * t1[(2 * q8) ^ twi] + hi * t1[(2 * q8 + 1) ^ twi];
            }
            float u0 = a0.x + a0.y, u1 = a1.x + a1.y;
            if (i & 1) { v0[i >> 1].y = u0; v1[i >> 1].y = u1; }
            else       { v0[i >> 1].x = u0; v1[i >> 1].x = u1; }
        }
    }

    float dn0, dn1;
    jacobi_blk(v0, v1, g, SW1, dn0, dn1);

    // W1 -> global (row-pair v2f stores)
    float* op = w1out + gm * 1024 + c0;
    #pragma unroll
    for (int j = 0; j < 16; ++j) {
        *(v2f*)&op[(2 * j) * 32]     = mk2(v0[j].x, v1[j].x);
        *(v2f*)&op[(2 * j + 1) * 32] = mk2(v0[j].y, v1[j].y);
    }

    // log-eigen stats
    const float ls0 = 0.5f * logf(dn0), ls1 = 0.5f * logf(dn1);
    const float invN = 1.0f / (float)NMAT;
    const float g0 = ls0 * __builtin_amdgcn_rcpf(dn0) * invN;
    const float g1 = ls1 * __builtin_amdgcn_rcpf(dn1) * invN;
    {
        float s1v = ls0 + ls1, s2v = ls0 * ls0 + ls1 * ls1;
        #pragma unroll
        for (int m = 32; m >= 1; m >>= 1) {
            s1v += __shfl_xor(s1v, m, 64);
            s2v += __shfl_xor(s2v, m, 64);
        }
        if (lane == 0) { atomicAdd(&S1B, s1v); atomicAdd(&S2B, s2v); }
    }

    // GT recon: 4-stage take-turns tile per wave
    float accR[16];
    #pragma unroll
    for (int i = 0; i < 16; ++i) accR[i] = 0.f;
    const int cc = lane & 31, half = lane >> 5;
    const int cm = cc & 15, cbase = cc * 32;

    #pragma unroll 1
    for (int s = 0; s < 4; ++s) {
        if (q == s) {
            #pragma unroll
            for (int j = 0; j < 16; ++j) {
                *(v2f*)&tw[(2 * j) * 32 + 2 * (g ^ ((2 * j) & 15))]         = mk2(v0[j].x, v1[j].x);
                *(v2f*)&tw[(2 * j + 1) * 32 + 2 * (g ^ ((2 * j + 1) & 15))] = mk2(v0[j].y, v1[j].y);
            }
            *(v2f*)&GB[wv][s][c0] = mk2(g0, g1);
        }
        wave_fence();
        v2f gr[16];
        #pragma unroll
        for (int p2 = 0; p2 < 16; ++p2) {
            v2f wr = *(const v2f*)&tw[cbase + 2 * (p2 ^ cm)];
            v2f gg = *(const v2f*)&GB[wv][s][2 * p2];
            gr[p2] = gg * wr;
        }
        #pragma unroll
        for (int i = 0; i < 16; ++i) {
            const int r = half * 16 + i;
            const int rw = r & 15;
            v2f acc = {0.f, 0.f};
            #pragma unroll
            for (int q8 = 0; q8 < 8; ++q8) {
                v4f f = *(const v4f*)&tw[r * 32 + 4 * q8];
                v2f lo = {f.x, f.y}, hi = {f.z, f.w};
                acc += lo * gr[(2 * q8) ^ rw] + hi * gr[(2 * q8 + 1) ^ rw];
            }
            accR[i] += acc.x + acc.y;
        }
        wave_fence();
    }
    #pragma unroll
    for (int i = 0; i < 16; ++i)
        atomicAdd(&ACC[(half * 16 + i) * 32 + cc], accR[i]);
    __syncthreads();
    for (int e = tid; e < 1024; e += 256) atomicAdd(ws + WS_GT + e, ACC[e]);
    if (tid == 0) {
        atomicAdd(ws + WS_S1, S1B * invN);
        atomicAdd(ws + WS_S2, S2B * invN);
    }
}

// ---------------------------------------------------------------------------
// K4: E = exp(GT); Gn = Gs E Gs; Gh = Gn^{-1/2}; K = Gh*Gs; p from S1,S2.
// ---------------------------------------------------------------------------
__global__ __launch_bounds__(64) void k_karcher(float* __restrict__ ws) {
    __shared__ float LA[32 * SP];
    __shared__ float LB[32 * SP];
    const int lane = threadIdx.x;
    const int col  = lane & 31;
    const int base = lane & 32;

    for (int e = lane; e < 1024; e += 64)
        LB[(e >> 5) * SP + (e & 31)] = ws[WS_GS + e];
    v2f gsc[16];
    #pragma unroll
    for (int j = 0; j < 16; ++j) {
        gsc[j].x = ws[WS_GS + (2 * j) * 32 + col];
        gsc[j].y = ws[WS_GS + (2 * j + 1) * 32 + col];
    }
    v2f w[16];
    #pragma unroll
    for (int j = 0; j < 16; ++j) {
        w[j].x = ws[WS_GT + (2 * j) * 32 + col];
        w[j].y = ws[WS_GT + (2 * j + 1) * 32 + col];
    }
    v2f cn2 = {0.f, 0.f};
    #pragma unroll
    for (int j = 0; j < 16; ++j) cn2 += w[j] * w[j];
    float fro2 = cn2.x + cn2.y;
    #pragma unroll
    for (int m = 16; m >= 1; m >>= 1) fro2 += __shfl_xor(fro2, m, 64);
    const float shift = __builtin_amdgcn_sqrtf(fro2) + 0.01f;
    #pragma unroll
    for (int j = 0; j < 16; ++j) {
        w[j].x += (2 * j     == col) ? shift : 0.f;
        w[j].y += (2 * j + 1 == col) ? shift : 0.f;
    }
    const float dn = jacobi_fg(w, col, SW_SINGLE);
    put_col(LA, w, col);
    __syncthreads();
    const float lam = __builtin_amdgcn_sqrtf(dn) - shift;
    const float ce  = expf(lam) * __builtin_amdgcn_rcpf(dn);
    v2f ec[16];
    recon_col(LA, ce, col, base, ec);
    __syncthreads();
    put_col(LA, ec, col);
    __syncthreads();
    v2f u[16], gn[16];
    colmm(LA, gsc, u);
    colmm(LB, u, gn);
    const float dn2 = jacobi_fg(gn, col, SW_SINGLE);
    __syncthreads();
    put_col(LA, gn, col);
    __syncthreads();
    const float lam2 = __builtin_amdgcn_sqrtf(dn2);
    const float ch   = __builtin_amdgcn_rsqf(lam2) * __builtin_amdgcn_rcpf(dn2);
    v2f gh[16];
    recon_col(LA, ch, col, base, gh);
    __syncthreads();
    put_col(LA, gh, col);
    __syncthreads();
    v2f kc[16];
    colmm(LA, gsc, kc);
    #pragma unroll
    for (int j = 0; j < 16; ++j) {
        ws[WS_K + (2 * j) * 32 + col]     = kc[j].x;
        ws[WS_K + (2 * j + 1) * 32 + col] = kc[j].y;
    }
    if (lane == 0) {
        const float S1  = ws[WS_S1];
        const float S2  = ws[WS_S2];
        const float var = S2 - S1 * S1 * 0.03125f;
        ws[WS_P] = __builtin_amdgcn_rsqf(var + 1e-5f);
    }
}

// ---------------------------------------------------------------------------
// K5 (fused warm+final): F = K W1 diag(lam1^{-1/2}); blocked Jacobi;
// Y = C W2 diag(lam^{(p-1)/2}); out = Y Y^T (4-stage take-turns tile).
// ---------------------------------------------------------------------------
__global__ __launch_bounds__(256) void k_fused(float* __restrict__ out,
                                               const float* __restrict__ ws) {
    __shared__ float KL[1024];
    __shared__ float CL[1024];
    __shared__ float TW[4][1024];
    const int tid = threadIdx.x;
    for (int e = tid; e < 1024; e += 256) {
        KL[e] = ws[WS_K + e];
        CL[e] = ws[WS_C + e];
    }
    __syncthreads();

    const int lane = tid & 63;
    const int wv   = tid >> 6;
    const int q    = lane >> 4;
    const int g    = lane & 15;
    const int c0   = 2 * g;
    const size_t gmbase = (size_t)blockIdx.x * 16 + wv * 4;
    const size_t gm = gmbase + q;
    float* tw = TW[wv];
    const float p = ws[WS_P];

    v2f v0[16], v1[16];
    {   // load + scale + K-multiply scoped
        const float* wp = out + gm * 1024 + c0;
        v2f t0[16], t1[16];
        #pragma unroll
        for (int j = 0; j < 16; ++j) {
            v2f la = *(const v2f*)&wp[(2 * j) * 32];
            v2f lb = *(const v2f*)&wp[(2 * j + 1) * 32];
            t0[j] = mk2(la.x, lb.x);
            t1[j] = mk2(la.y, lb.y);
        }
        const float nn0 = nrm16(t0), nn1 = nrm16(t1);
        const float sc0 = __builtin_amdgcn_rsqf(__builtin_amdgcn_sqrtf(nn0));
        const float sc1 = __builtin_amdgcn_rsqf(__builtin_amdgcn_sqrtf(nn1));
        const v2f sv0 = {sc0, sc0}, sv1 = {sc1, sc1};
        #pragma unroll
        for (int j = 0; j < 16; ++j) { t0[j] *= sv0; t1[j] *= sv1; }
        #pragma unroll
        for (int i = 0; i < 32; ++i) {
            v2f a0 = {0.f, 0.f}, a1 = {0.f, 0.f};
            #pragma unroll
            for (int q8 = 0; q8 < 8; ++q8) {
                v4f f = *(const v4f*)&KL[i * 32 + 4 * q8];
                v2f lo = {f.x, f.y}, hi = {f.z, f.w};
                a0 += lo * t0[2 * q8] + hi * t0[2 * q8 + 1];
                a1 += lo * t1[2 * q8] + hi * t1[2 * q8 + 1];
            }
            float u0 = a0.x + a0.y, u1 = a1.x + a1.y;
            if (i & 1) { v0[i >> 1].y = u0; v1[i >> 1].y = u1; }
            else       { v0[i >> 1].x = u0; v1[i >> 1].x = u1; }
        }
    }

    float dn0, dn1;
    jacobi_blk(v0, v1, g, SW2, dn0, dn1);   // dn = lambda (factor form)

    const float dj0 = exp2f(log2f(dn0) * 0.5f * (p - 1.0f));
    const float dj1 = exp2f(log2f(dn1) * 0.5f * (p - 1.0f));
    const v2f dv0 = {dj0, dj0}, dv1 = {dj1, dj1};
    v2f y0[16], y1[16];
    {
        v2f t0[16], t1[16];
        #pragma unroll
        for (int j = 0; j < 16; ++j) { t0[j] = v0[j] * dv0; t1[j] = v1[j] * dv1; }
        #pragma unroll
        for (int i = 0; i < 32; ++i) {
            v2f a0 = {0.f, 0.f}, a1 = {0.f, 0.f};
            #pragma unroll
            for (int q8 = 0; q8 < 8; ++q8) {
                v4f f = *(const v4f*)&CL[i * 32 + 4 * q8];
                v2f lo = {f.x, f.y}, hi = {f.z, f.w};
                a0 += lo * t0[2 * q8] + hi * t0[2 * q8 + 1];
                a1 += lo * t1[2 * q8] + hi * t1[2 * q8 + 1];
            }
            float u0 = a0.x + a0.y, u1 = a1.x + a1.y;
            if (i & 1) { y0[i >> 1].y = u0; y1[i >> 1].y = u1; }
            else       { y0[i >> 1].x = u0; y1[i >> 1].x = u1; }
        }
    }

    // out = Y Y^T, 4-stage take-turns tile
    const int cc = lane & 31, half = lane >> 5;
    const int cm = cc & 15, cbase = cc * 32;
    #pragma unroll 1
    for (int s = 0; s < 4; ++s) {
        if (q == s) {
            #pragma unroll
            for (int j = 0; j < 16; ++j) {
                *(v2f*)&tw[(2 * j) * 32 + 2 * (g ^ ((2 * j) & 15))]         = mk2(y0[j].x, y1[j].x);
                *(v2f*)&tw[(2 * j + 1) * 32 + 2 * (g ^ ((2 * j + 1) & 15))] = mk2(y0[j].y, y1[j].y);
            }
        }
        wave_fence();
        v2f yc[16];
        #pragma unroll
        for (int p2 = 0; p2 < 16; ++p2)
            yc[p2] = *(const v2f*)&tw[cbase + 2 * (p2 ^ cm)];
        const size_t gmo = gmbase + s;
        #pragma unroll
        for (int i = 0; i < 16; ++i) {
            const int r = half * 16 + i;
            const int rw = r & 15;
            v2f acc = {0.f, 0.f};
            #pragma unroll
            for (int q8 = 0; q8 < 8; ++q8) {
                v4f f = *(const v4f*)&tw[r * 32 + 4 * q8];
                v2f lo = {f.x, f.y}, hi = {f.z, f.w};
                acc += lo * yc[(2 * q8) ^ rw] + hi * yc[(2 * q8 + 1) ^ rw];
            }
            out[gmo * 1024 + r * 32 + cc] = acc.x + acc.y;
        }
        wave_fence();
    }
}

extern "C" void kernel_launch(void* const* d_in, const int* in_sizes, int n_in,
                              void* d_out, int out_size, void* d_ws, size_t ws_size,
                              hipStream_t stream) {
    const float* X = (const float*)d_in[0];
    const float* R = (const float*)d_in[1];
    const float* B = (const float*)d_in[2];
    float* out = (float*)d_out;
    float* ws  = (float*)d_ws;

    hipMemsetAsync(d_ws, 0, WS_TOTAL * sizeof(float), stream);
    k_mean<<<NMAT / 16, 256, 0, stream>>>(X, ws);
    k_small_prep<<<2, 64, 0, stream>>>(R, B, ws);
    k_batch_log<<<NMAT / 16, 256, 0, stream>>>(X, out, ws);
    k_karcher<<<1, 64, 0, stream>>>(ws);
    k_fused<<<NMAT / 16, 256, 0, stream>>>(out, ws);
}

// Round 14
// 1651.377 us; speedup vs baseline: 2.8721x; 1.0450x over previous
//
#include <hip/hip_runtime.h>
#include <math.h>

typedef float v2f __attribute__((ext_vector_type(2)));
typedef float v4f __attribute__((ext_vector_type(4)));

#define NMAT 32768
#define SW1 4          // pass-1 sweeps
#define SW2 2          // pass-2 sweeps (SW2=1 measured absmax 0.059 > 0.056)
#define SW_SINGLE 10   // single-matrix eigs
#define SP 34          // padded row stride for single-wave LDS matrices

// workspace float offsets
#define WS_G    0
#define WS_GS   1024
#define WS_GIS  2048
#define WS_GT   3072
#define WS_K    4096
#define WS_C    5120
#define WS_S1   6144
#define WS_S2   6145
#define WS_P    6146
#define WS_TOTAL 6400

__device__ __forceinline__ int swz(int r, int c) {
    return r * 32 + 2 * ((c >> 1) ^ (r & 15)) + (c & 1);
}
__device__ __forceinline__ void wave_fence() {
    asm volatile("s_waitcnt lgkmcnt(0)" ::: "memory");
}
__device__ __forceinline__ v2f mk2(float a, float b) { v2f r; r.x = a; r.y = b; return r; }

// xor-shuffle: CTRL!=0 -> VALU DPP (quad_perm m=1,2,3; row_half_mirror 0x141
// = lane^7; row_mirror 0x140 = lane^15 — verified working in r13).
// CTRL==0 -> DS shuffle.
template<int CTRL>
__device__ __forceinline__ float xsh(float x, int m) {
    if constexpr (CTRL != 0) {
        return __int_as_float(__builtin_amdgcn_update_dpp(
            __float_as_int(x), __float_as_int(x), CTRL, 0xF, 0xF, true));
    } else {
        return __shfl_xor(x, m, 64);
    }
}

__device__ __forceinline__ float nrm16(const v2f (&v)[16]) {
    v2f n0 = v[0] * v[0], n1 = v[1] * v[1], n2 = v[2] * v[2], n3 = v[3] * v[3];
    #pragma unroll
    for (int j = 4; j < 16; j += 4) {
        n0 += v[j] * v[j];     n1 += v[j + 1] * v[j + 1];
        n2 += v[j + 2] * v[j + 2]; n3 += v[j + 3] * v[j + 3];
    }
    v2f nt = (n0 + n1) + (n2 + n3);
    return nt.x + nt.y;
}

// ---------------------------------------------------------------------------
// Symmetric fast-Givens rotation on column pair (X,Y); deterministic d==0
// tie-break via `low` (partner computes !low -> t flips exactly).
// ---------------------------------------------------------------------------
__device__ __forceinline__ void rot2(v2f (&X)[16], v2f (&Y)[16],
                                     float& dnX, float& dnY,
                                     float& sX, float& rsX,
                                     float& sY, float& rsY, bool low) {
    v2f p0 = X[0] * Y[0], p1 = X[1] * Y[1], p2 = X[2] * Y[2], p3 = X[3] * Y[3];
    #pragma unroll
    for (int j = 4; j < 16; j += 4) {
        p0 += X[j] * Y[j];         p1 += X[j + 1] * Y[j + 1];
        p2 += X[j + 2] * Y[j + 2]; p3 += X[j + 3] * Y[j + 3];
    }
    v2f pt = (p0 + p1) + (p2 + p3);
    const float raw = pt.x + pt.y;
    const float apq = (sX * sY) * raw;
    const float b   = apq + apq;
    const float d   = dnY - dnX;
    const float r2  = __builtin_fmaf(d, d, b * b);
    const float sr  = __builtin_amdgcn_sqrtf(r2);
    const float u   = fmaxf(fabsf(d) + sr, 1e-30f);
    const bool  neg = (d < 0.f) || (d == 0.f && !low);
    const float t   = (neg ? -b : b) * __builtin_amdgcn_rcpf(u);
    const float s1f = __builtin_fmaf(t, t, 1.f);
    const float c   = __builtin_amdgcn_rsqf(s1f);
    const float rc  = c * s1f;
    const float gX  = -t * (sY * rsX);
    const float gY  =  t * (sX * rsY);
    const v2f gX2 = {gX, gX}, gY2 = {gY, gY};
    #pragma unroll
    for (int j = 0; j < 16; ++j) {
        const v2f yo = Y[j];
        Y[j] = yo + gY2 * X[j];
        X[j] = X[j] + gX2 * yo;
    }
    dnX = __builtin_fmaf(-t, apq, dnX);
    dnY = __builtin_fmaf( t, apq, dnY);
    sX *= c; rsX *= rc;
    sY *= c; rsY *= rc;
}

// One tournament meeting vs group g^m.
template<int CTRL>
__device__ __forceinline__ void meeting(v2f (&v0)[16], v2f (&v1)[16],
                                        float& dn0, float& dn1,
                                        float& s0, float& rs0,
                                        float& s1_, float& rs1, int m, int g) {
    const bool low = g < (g ^ m);
    v2f c0[16], c1[16];
    #pragma unroll
    for (int j = 0; j < 16; ++j) {
        c0[j].x = xsh<CTRL>(v0[j].x, m);
        c0[j].y = xsh<CTRL>(v0[j].y, m);
    }
    float cdn0 = xsh<CTRL>(dn0, m), cs0 = xsh<CTRL>(s0, m), crs0 = xsh<CTRL>(rs0, m);
    #pragma unroll
    for (int j = 0; j < 16; ++j) {
        c1[j].x = xsh<CTRL>(v1[j].x, m);
        c1[j].y = xsh<CTRL>(v1[j].y, m);
    }
    float cdn1 = xsh<CTRL>(dn1, m), cs1 = xsh<CTRL>(s1_, m), crs1 = xsh<CTRL>(rs1, m);
    rot2(v0, c0, dn0, cdn0, s0, rs0, cs0, crs0, low);
    rot2(v1, c1, dn1, cdn1, s1_, rs1, cs1, crs1, low);
    rot2(v0, c1, dn0, cdn1, s0, rs0, cs1, crs1, low);
    rot2(v1, c0, dn1, cdn0, s1_, rs1, cs0, crs0, low);
}

// ---------------------------------------------------------------------------
// Blocked one-sided Jacobi: lane owns cols {2g,2g+1}; 16 lanes/matrix;
// 4 matrices/wave. Masks 1,2,3,7,15 on VALU DPP; rest DS.
// ---------------------------------------------------------------------------
__device__ __forceinline__ void jacobi_blk(v2f (&v0)[16], v2f (&v1)[16], int g,
                                           int sweeps, float& odn0, float& odn1) {
    #pragma unroll 1
    for (int sw = 0; sw < sweeps; ++sw) {
        float dn0 = nrm16(v0), dn1 = nrm16(v1);
        float s0 = 1.f, rs0 = 1.f, s1_ = 1.f, rs1 = 1.f;
        rot2(v0, v1, dn0, dn1, s0, rs0, s1_, rs1, true);  // intra pair
        meeting<0xB1>(v0, v1, dn0, dn1, s0, rs0, s1_, rs1, 1, g);
        meeting<0x4E>(v0, v1, dn0, dn1, s0, rs0, s1_, rs1, 2, g);
        meeting<0x1B>(v0, v1, dn0, dn1, s0, rs0, s1_, rs1, 3, g);
        #pragma unroll 1
        for (int m = 4; m <= 6; ++m)
            meeting<0>(v0, v1, dn0, dn1, s0, rs0, s1_, rs1, m, g);
        meeting<0x141>(v0, v1, dn0, dn1, s0, rs0, s1_, rs1, 7, g);
        #pragma unroll 1
        for (int m = 8; m <= 14; ++m)
            meeting<0>(v0, v1, dn0, dn1, s0, rs0, s1_, rs1, m, g);
        meeting<0x140>(v0, v1, dn0, dn1, s0, rs0, s1_, rs1, 15, g);
        const v2f f0 = {s0, s0}, f1 = {s1_, s1_};
        #pragma unroll
        for (int j = 0; j < 16; ++j) { v0[j] *= f0; v1[j] *= f1; }
    }
    odn0 = nrm16(v0);
    odn1 = nrm16(v1);
}

// ---------------------------------------------------------------------------
// Single-wave 1-col Jacobi (k_small_prep / k_karcher only). r11-proven
// semantics: t computed identically on both lanes; sign asymmetry via isp.
// ---------------------------------------------------------------------------
template<int CTRL>
__device__ __forceinline__ void jac_round(v2f (&v)[16], int col, int m,
                                          float& dn, float& sc, float& rsc) {
    const float dnq = xsh<CTRL>(dn, m);
    const float dq  = xsh<CTRL>(sc, m);
    v2f o[16];
    #pragma unroll
    for (int j = 0; j < 16; ++j) {
        o[j].x = xsh<CTRL>(v[j].x, m);
        o[j].y = xsh<CTRL>(v[j].y, m);
    }
    v2f p0 = v[0] * o[0], p1 = v[1] * o[1], p2 = v[2] * o[2], p3 = v[3] * o[3];
    #pragma unroll
    for (int j = 4; j < 16; j += 4) {
        p0 += v[j] * o[j];     p1 += v[j + 1] * o[j + 1];
        p2 += v[j + 2] * o[j + 2]; p3 += v[j + 3] * o[j + 3];
    }
    v2f pt = (p0 + p1) + (p2 + p3);
    const float raw = pt.x + pt.y;
    const bool  isp = col < (col ^ m);
    const float apq = (sc * dq) * raw;
    const float b   = apq + apq;
    const float d   = isp ? (dnq - dn) : (dn - dnq);
    const float r2  = __builtin_fmaf(d, d, b * b);
    const float sr  = __builtin_amdgcn_sqrtf(r2);
    const float u   = fmaxf(fabsf(d) + sr, 1e-30f);
    const float t   = (d < 0.f ? -b : b) * __builtin_amdgcn_rcpf(u);
    const float s1  = __builtin_fmaf(t, t, 1.f);
    const float c   = __builtin_amdgcn_rsqf(s1);
    const float gam = t * (dq * rsc);
    const float gs  = isp ? -gam : gam;
    const v2f gs2 = {gs, gs};
    #pragma unroll
    for (int j = 0; j < 16; ++j) v[j] += gs2 * o[j];
    sc *= c; rsc *= c * s1;
    dn = __builtin_fmaf(isp ? -t : t, apq, dn);
}

__device__ __forceinline__ float jacobi_fg(v2f (&v)[16], int col, int sweeps) {
    #pragma unroll 1
    for (int sweep = 0; sweep < sweeps; ++sweep) {
        float dn = nrm16(v);
        float sc = 1.f, rsc = 1.f;
        jac_round<0xB1>(v, col, 1, dn, sc, rsc);
        jac_round<0x4E>(v, col, 2, dn, sc, rsc);
        jac_round<0x1B>(v, col, 3, dn, sc, rsc);
        #pragma unroll 1
        for (int m = 4; m <= 6; ++m) jac_round<0>(v, col, m, dn, sc, rsc);
        jac_round<0x141>(v, col, 7, dn, sc, rsc);
        #pragma unroll 1
        for (int m = 8; m <= 14; ++m) jac_round<0>(v, col, m, dn, sc, rsc);
        jac_round<0x140>(v, col, 15, dn, sc, rsc);
        #pragma unroll 1
        for (int m = 16; m < 32; ++m) jac_round<0>(v, col, m, dn, sc, rsc);
        const v2f s2 = {sc, sc};
        #pragma unroll
        for (int j = 0; j < 16; ++j) v[j] *= s2;
    }
    return nrm16(v);
}

__device__ __forceinline__ void put_col(float* L, const v2f (&w)[16], int col) {
    #pragma unroll
    for (int j = 0; j < 16; ++j) {
        L[(2 * j) * SP + col]     = w[j].x;
        L[(2 * j + 1) * SP + col] = w[j].y;
    }
}

__device__ __forceinline__ void colmm(const float* L, const v2f (&y)[16], v2f (&z)[16]) {
    #pragma unroll
    for (int i = 0; i < 32; ++i) {
        v2f acc = {0.f, 0.f};
        #pragma unroll
        for (int q = 0; q < 16; ++q) {
            v2f mm = *(const v2f*)&L[i * SP + 2 * q];
            acc += mm * y[q];
        }
        float zi = acc.x + acc.y;
        if (i & 1) z[i >> 1].y = zi; else z[i >> 1].x = zi;
    }
}

__device__ __forceinline__ void recon_col(const float* LW, float coef, int col,
                                          int base, v2f (&z)[16]) {
    float rv[32];
    #pragma unroll
    for (int k = 0; k < 32; ++k) rv[k] = LW[col * SP + k];
    v2f y[16];
    #pragma unroll
    for (int q = 0; q < 16; ++q) {
        y[q].x = __shfl(coef, base | (2 * q), 64)     * rv[2 * q];
        y[q].y = __shfl(coef, base | (2 * q + 1), 64) * rv[2 * q + 1];
    }
    colmm(LW, y, z);
}

// ---------------------------------------------------------------------------
// K1a: per-block partial sums of 16 matrices -> scratch (d_out, free here)
// ---------------------------------------------------------------------------
__global__ __launch_bounds__(256) void k_mean1(const float* __restrict__ X,
                                               float* __restrict__ scratch) {
    const int t = threadIdx.x;
    const size_t base = (size_t)blockIdx.x * 16 * 1024;
    float4 a = {0.f, 0.f, 0.f, 0.f};
    for (int m = 0; m < 16; ++m) {
        float4 f = *(const float4*)&X[base + (size_t)m * 1024 + t * 4];
        a.x += f.x; a.y += f.y; a.z += f.z; a.w += f.w;
    }
    *(float4*)&scratch[(size_t)blockIdx.x * 1024 + t * 4] = a;
}

// K1b: reduce 2048 partials -> ws[WS_G]
__global__ __launch_bounds__(256) void k_mean2(const float* __restrict__ scratch,
                                               float* __restrict__ ws) {
    const int e = blockIdx.x * 256 + threadIdx.x;   // 4 blocks x 256 = 1024
    float a = 0.f;
    for (int p = 0; p < 2048; ++p) a += scratch[(size_t)p * 1024 + e];
    ws[WS_G + e] = a * (1.0f / (float)NMAT);
}

// ---------------------------------------------------------------------------
// K2: block 0: eig(G) -> Gs, Gis.  block 1: eig(B) -> C = B^{1/2} R.
// ---------------------------------------------------------------------------
__global__ __launch_bounds__(64) void k_small_prep(const float* __restrict__ R,
                                                   const float* __restrict__ B,
                                                   float* __restrict__ ws) {
    __shared__ float LW[32 * SP];
    const int lane = threadIdx.x;
    const int col  = lane & 31;
    const int base = lane & 32;
    if (blockIdx.x == 0) {
        v2f w[16];
        #pragma unroll
        for (int j = 0; j < 16; ++j) {
            w[j].x = ws[WS_G + (2 * j) * 32 + col];
            w[j].y = ws[WS_G + (2 * j + 1) * 32 + col];
        }
        const float dn = jacobi_fg(w, col, SW_SINGLE);
        put_col(LW, w, col);
        __syncthreads();
        const float lam = __builtin_amdgcn_sqrtf(dn);
        const float cs  = __builtin_amdgcn_sqrtf(lam) * __builtin_amdgcn_rcpf(dn);
        const float cis = __builtin_amdgcn_rsqf(lam)  * __builtin_amdgcn_rcpf(dn);
        v2f z[16];
        recon_col(LW, cs, col, base, z);
        #pragma unroll
        for (int j = 0; j < 16; ++j) {
            ws[WS_GS + (2 * j) * 32 + col]     = z[j].x;
            ws[WS_GS + (2 * j + 1) * 32 + col] = z[j].y;
        }
        recon_col(LW, cis, col, base, z);
        #pragma unroll
        for (int j = 0; j < 16; ++j) {
            ws[WS_GIS + (2 * j) * 32 + col]     = z[j].x;
            ws[WS_GIS + (2 * j + 1) * 32 + col] = z[j].y;
        }
    } else {
        v2f w[16];
        #pragma unroll
        for (int j = 0; j < 16; ++j) {
            w[j].x = B[(2 * j) * 32 + col];
            w[j].y = B[(2 * j + 1) * 32 + col];
        }
        const float dn = jacobi_fg(w, col, SW_SINGLE);
        put_col(LW, w, col);
        __syncthreads();
        const float lam = __builtin_amdgcn_sqrtf(dn);
        const float cbs = __builtin_amdgcn_sqrtf(lam) * __builtin_amdgcn_rcpf(dn);
        v2f bs[16];
        recon_col(LW, cbs, col, base, bs);
        __syncthreads();
        put_col(LW, bs, col);
        __syncthreads();
        v2f r[16];
        #pragma unroll
        for (int j = 0; j < 16; ++j) {
            r[j].x = R[(2 * j) * 32 + col];
            r[j].y = R[(2 * j + 1) * 32 + col];
        }
        v2f c[16];
        colmm(LW, r, c);
        #pragma unroll
        for (int j = 0; j < 16; ++j) {
            ws[WS_C + (2 * j) * 32 + col]     = c[j].x;
            ws[WS_C + (2 * j + 1) * 32 + col] = c[j].y;
        }
    }
}

// ---------------------------------------------------------------------------
// K3 (pass 1): M = Gis X Gis; blocked Jacobi (4 mat/wave); W1 -> w1out;
// GT/S1/S2 accumulation.
// ---------------------------------------------------------------------------
__global__ __launch_bounds__(256) void k_batch_log(const float* __restrict__ X,
                                                   float* __restrict__ w1out,
                                                   float* __restrict__ ws) {
    __shared__ float HL[1024];       // Gis, pair-swizzled
    __shared__ float TW[4][1024];    // per-wave take-turns W tile
    __shared__ float GB[4][4][32];   // per-wave, per-stage g coefficients
    __shared__ float ACC[1024];
    __shared__ float S1B, S2B;
    const int tid = threadIdx.x;
    if (tid == 0) { S1B = 0.f; S2B = 0.f; }
    for (int e = tid; e < 1024; e += 256) {
        int r = e >> 5, c = e & 31;
        HL[swz(r, c)] = ws[WS_GIS + e];
        ACC[e] = 0.f;
    }
    __syncthreads();

    const int lane = tid & 63;
    const int wv   = tid >> 6;
    const int q    = lane >> 4;          // matrix quarter within wave
    const int g    = lane & 15;          // group (owns cols 2g, 2g+1)
    const int c0   = 2 * g;
    const size_t gm = (size_t)blockIdx.x * 16 + wv * 4 + q;
    const float* Xm = X + gm * 1024;
    float* tw = TW[wv];

    v2f v0[16], v1[16];
    {   // congruence temporaries scoped
        v2f h0[16], h1[16];
        const int e0 = c0 & 15, e1 = (c0 + 1) & 15;
        #pragma unroll
        for (int p = 0; p < 16; ++p) {
            h0[p] = *(const v2f*)&HL[c0 * 32 + 2 * (p ^ e0)];
            h1[p] = *(const v2f*)&HL[(c0 + 1) * 32 + 2 * (p ^ e1)];
        }
        v2f t0[16], t1[16];
        #pragma unroll
        for (int i = 0; i < 32; ++i) {
            const float4* row = (const float4*)(Xm + i * 32);
            v2f a0 = {0.f, 0.f}, a1 = {0.f, 0.f};
            #pragma unroll
            for (int q8 = 0; q8 < 8; ++q8) {
                float4 f = row[q8];
                v2f lo = {f.x, f.y}, hi = {f.z, f.w};
                a0 += lo * h0[2 * q8] + hi * h0[2 * q8 + 1];
                a1 += lo * h1[2 * q8] + hi * h1[2 * q8 + 1];
            }
            float u0 = a0.x + a0.y, u1 = a1.x + a1.y;
            if (i & 1) { t0[i >> 1].y = u0; t1[i >> 1].y = u1; }
            else       { t0[i >> 1].x = u0; t1[i >> 1].x = u1; }
        }
        #pragma unroll
        for (int i = 0; i < 32; ++i) {
            const int twi = i & 15;
            v2f a0 = {0.f, 0.f}, a1 = {0.f, 0.f};
            #pragma unroll
            for (int q8 = 0; q8 < 8; ++q8) {
                v4f f = *(const v4f*)&HL[i * 32 + 4 * q8];
                v2f lo = {f.x, f.y}, hi = {f.z, f.w};
                a0 += lo * t0[(2 * q8) ^ twi] + hi * t0[(2 * q8 + 1) ^ twi];
                a1 += lo * t1[(2 * q8) ^ twi] + hi * t1[(2 * q8 + 1) ^ twi];
            }
            float u0 = a0.x + a0.y, u1 = a1.x + a1.y;
            if (i & 1) { v0[i >> 1].y = u0; v1[i >> 1].y = u1; }
            else       { v0[i >> 1].x = u0; v1[i >> 1].x = u1; }
        }
    }

    float dn0, dn1;
    jacobi_blk(v0, v1, g, SW1, dn0, dn1);

    // W1 -> global (row-pair v2f stores)
    float* op = w1out + gm * 1024 + c0;
    #pragma unroll
    for (int j = 0; j < 16; ++j) {
        *(v2f*)&op[(2 * j) * 32]     = mk2(v0[j].x, v1[j].x);
        *(v2f*)&op[(2 * j + 1) * 32] = mk2(v0[j].y, v1[j].y);
    }

    // log-eigen stats
    const float ls0 = 0.5f * logf(dn0), ls1 = 0.5f * logf(dn1);
    const float invN = 1.0f / (float)NMAT;
    const float g0 = ls0 * __builtin_amdgcn_rcpf(dn0) * invN;
    const float g1 = ls1 * __builtin_amdgcn_rcpf(dn1) * invN;
    {
        float s1v = ls0 + ls1, s2v = ls0 * ls0 + ls1 * ls1;
        #pragma unroll
        for (int m = 32; m >= 1; m >>= 1) {
            s1v += __shfl_xor(s1v, m, 64);
            s2v += __shfl_xor(s2v, m, 64);
        }
        if (lane == 0) { atomicAdd(&S1B, s1v); atomicAdd(&S2B, s2v); }
    }

    // GT recon: 4-stage take-turns tile per wave
    float accR[16];
    #pragma unroll
    for (int i = 0; i < 16; ++i) accR[i] = 0.f;
    const int cc = lane & 31, half = lane >> 5;
    const int cm = cc & 15, cbase = cc * 32;

    #pragma unroll 1
    for (int s = 0; s < 4; ++s) {
        if (q == s) {
            #pragma unroll
            for (int j = 0; j < 16; ++j) {
                *(v2f*)&tw[(2 * j) * 32 + 2 * (g ^ ((2 * j) & 15))]         = mk2(v0[j].x, v1[j].x);
                *(v2f*)&tw[(2 * j + 1) * 32 + 2 * (g ^ ((2 * j + 1) & 15))] = mk2(v0[j].y, v1[j].y);
            }
            *(v2f*)&GB[wv][s][c0] = mk2(g0, g1);
        }
        wave_fence();
        v2f gr[16];
        #pragma unroll
        for (int p2 = 0; p2 < 16; ++p2) {
            v2f wr = *(const v2f*)&tw[cbase + 2 * (p2 ^ cm)];
            v2f gg = *(const v2f*)&GB[wv][s][2 * p2];
            gr[p2] = gg * wr;
        }
        #pragma unroll
        for (int i = 0; i < 16; ++i) {
            const int r = half * 16 + i;
            const int rw = r & 15;
            v2f acc = {0.f, 0.f};
            #pragma unroll
            for (int q8 = 0; q8 < 8; ++q8) {
                v4f f = *(const v4f*)&tw[r * 32 + 4 * q8];
                v2f lo = {f.x, f.y}, hi = {f.z, f.w};
                acc += lo * gr[(2 * q8) ^ rw] + hi * gr[(2 * q8 + 1) ^ rw];
            }
            accR[i] += acc.x + acc.y;
        }
        wave_fence();
    }
    #pragma unroll
    for (int i = 0; i < 16; ++i)
        atomicAdd(&ACC[(half * 16 + i) * 32 + cc], accR[i]);
    __syncthreads();
    for (int e = tid; e < 1024; e += 256) atomicAdd(ws + WS_GT + e, ACC[e]);
    if (tid == 0) {
        atomicAdd(ws + WS_S1, S1B * invN);
        atomicAdd(ws + WS_S2, S2B * invN);
    }
}

// ---------------------------------------------------------------------------
// K4: E = exp(GT); Gn = Gs E Gs; Gh = Gn^{-1/2}; K = Gh*Gs; p from S1,S2.
// ---------------------------------------------------------------------------
__global__ __launch_bounds__(64) void k_karcher(float* __restrict__ ws) {
    __shared__ float LA[32 * SP];
    __shared__ float LB[32 * SP];
    const int lane = threadIdx.x;
    const int col  = lane & 31;
    const int base = lane & 32;

    for (int e = lane; e < 1024; e += 64)
        LB[(e >> 5) * SP + (e & 31)] = ws[WS_GS + e];
    v2f gsc[16];
    #pragma unroll
    for (int j = 0; j < 16; ++j) {
        gsc[j].x = ws[WS_GS + (2 * j) * 32 + col];
        gsc[j].y = ws[WS_GS + (2 * j + 1) * 32 + col];
    }
    v2f w[16];
    #pragma unroll
    for (int j = 0; j < 16; ++j) {
        w[j].x = ws[WS_GT + (2 * j) * 32 + col];
        w[j].y = ws[WS_GT + (2 * j + 1) * 32 + col];
    }
    v2f cn2 = {0.f, 0.f};
    #pragma unroll
    for (int j = 0; j < 16; ++j) cn2 += w[j] * w[j];
    float fro2 = cn2.x + cn2.y;
    #pragma unroll
    for (int m = 16; m >= 1; m >>= 1) fro2 += __shfl_xor(fro2, m, 64);
    const float shift = __builtin_amdgcn_sqrtf(fro2) + 0.01f;
    #pragma unroll
    for (int j = 0; j < 16; ++j) {
        w[j].x += (2 * j     == col) ? shift : 0.f;
        w[j].y += (2 * j + 1 == col) ? shift : 0.f;
    }
    const float dn = jacobi_fg(w, col, SW_SINGLE);
    put_col(LA, w, col);
    __syncthreads();
    const float lam = __builtin_amdgcn_sqrtf(dn) - shift;
    const float ce  = expf(lam) * __builtin_amdgcn_rcpf(dn);
    v2f ec[16];
    recon_col(LA, ce, col, base, ec);
    __syncthreads();
    put_col(LA, ec, col);
    __syncthreads();
    v2f u[16], gn[16];
    colmm(LA, gsc, u);
    colmm(LB, u, gn);
    const float dn2 = jacobi_fg(gn, col, SW_SINGLE);
    __syncthreads();
    put_col(LA, gn, col);
    __syncthreads();
    const float lam2 = __builtin_amdgcn_sqrtf(dn2);
    const float ch   = __builtin_amdgcn_rsqf(lam2) * __builtin_amdgcn_rcpf(dn2);
    v2f gh[16];
    recon_col(LA, ch, col, base, gh);
    __syncthreads();
    put_col(LA, gh, col);
    __syncthreads();
    v2f kc[16];
    colmm(LA, gsc, kc);
    #pragma unroll
    for (int j = 0; j < 16; ++j) {
        ws[WS_K + (2 * j) * 32 + col]     = kc[j].x;
        ws[WS_K + (2 * j + 1) * 32 + col] = kc[j].y;
    }
    if (lane == 0) {
        const float S1  = ws[WS_S1];
        const float S2  = ws[WS_S2];
        const float var = S2 - S1 * S1 * 0.03125f;
        ws[WS_P] = __builtin_amdgcn_rsqf(var + 1e-5f);
    }
}

// ---------------------------------------------------------------------------
// K5 (fused warm+final): F = K W1 diag(lam1^{-1/2}); blocked 2-sweep Jacobi;
// Y = C W2 diag(lam^{(p-1)/2}); out = Y Y^T (4-stage take-turns tile).
// ---------------------------------------------------------------------------
__global__ __launch_bounds__(256) void k_fused(float* __restrict__ out,
                                               const float* __restrict__ ws) {
    __shared__ float KL[1024];
    __shared__ float CL[1024];
    __shared__ float TW[4][1024];
    const int tid = threadIdx.x;
    for (int e = tid; e < 1024; e += 256) {
        KL[e] = ws[WS_K + e];
        CL[e] = ws[WS_C + e];
    }
    __syncthreads();

    const int lane = tid & 63;
    const int wv   = tid >> 6;
    const int q    = lane >> 4;
    const int g    = lane & 15;
    const int c0   = 2 * g;
    const size_t gmbase = (size_t)blockIdx.x * 16 + wv * 4;
    const size_t gm = gmbase + q;
    float* tw = TW[wv];
    const float p = ws[WS_P];

    v2f v0[16], v1[16];
    {   // load + scale + K-multiply scoped
        const float* wp = out + gm * 1024 + c0;
        v2f t0[16], t1[16];
        #pragma unroll
        for (int j = 0; j < 16; ++j) {
            v2f la = *(const v2f*)&wp[(2 * j) * 32];
            v2f lb = *(const v2f*)&wp[(2 * j + 1) * 32];
            t0[j] = mk2(la.x, lb.x);
            t1[j] = mk2(la.y, lb.y);
        }
        const float nn0 = nrm16(t0), nn1 = nrm16(t1);
        const float sc0 = __builtin_amdgcn_rsqf(__builtin_amdgcn_sqrtf(nn0));
        const float sc1 = __builtin_amdgcn_rsqf(__builtin_amdgcn_sqrtf(nn1));
        const v2f sv0 = {sc0, sc0}, sv1 = {sc1, sc1};
        #pragma unroll
        for (int j = 0; j < 16; ++j) { t0[j] *= sv0; t1[j] *= sv1; }
        #pragma unroll
        for (int i = 0; i < 32; ++i) {
            v2f a0 = {0.f, 0.f}, a1 = {0.f, 0.f};
            #pragma unroll
            for (int q8 = 0; q8 < 8; ++q8) {
                v4f f = *(const v4f*)&KL[i * 32 + 4 * q8];
                v2f lo = {f.x, f.y}, hi = {f.z, f.w};
                a0 += lo * t0[2 * q8] + hi * t0[2 * q8 + 1];
                a1 += lo * t1[2 * q8] + hi * t1[2 * q8 + 1];
            }
            float u0 = a0.x + a0.y, u1 = a1.x + a1.y;
            if (i & 1) { v0[i >> 1].y = u0; v1[i >> 1].y = u1; }
            else       { v0[i >> 1].x = u0; v1[i >> 1].x = u1; }
        }
    }

    float dn0, dn1;
    jacobi_blk(v0, v1, g, SW2, dn0, dn1);   // dn = lambda (factor form)

    const float dj0 = exp2f(log2f(dn0) * 0.5f * (p - 1.0f));
    const float dj1 = exp2f(log2f(dn1) * 0.5f * (p - 1.0f));
    const v2f dv0 = {dj0, dj0}, dv1 = {dj1, dj1};
    v2f y0[16], y1[16];
    {
        v2f t0[16], t1[16];
        #pragma unroll
        for (int j = 0; j < 16; ++j) { t0[j] = v0[j] * dv0; t1[j] = v1[j] * dv1; }
        #pragma unroll
        for (int i = 0; i < 32; ++i) {
            v2f a0 = {0.f, 0.f}, a1 = {0.f, 0.f};
            #pragma unroll
            for (int q8 = 0; q8 < 8; ++q8) {
                v4f f = *(const v4f*)&CL[i * 32 + 4 * q8];
                v2f lo = {f.x, f.y}, hi = {f.z, f.w};
                a0 += lo * t0[2 * q8] + hi * t0[2 * q8 + 1];
                a1 += lo * t1[2 * q8] + hi * t1[2 * q8 + 1];
            }
            float u0 = a0.x + a0.y, u1 = a1.x + a1.y;
            if (i & 1) { y0[i >> 1].y = u0; y1[i >> 1].y = u1; }
            else       { y0[i >> 1].x = u0; y1[i >> 1].x = u1; }
        }
    }

    // out = Y Y^T, 4-stage take-turns tile
    const int cc = lane & 31, half = lane >> 5;
    const int cm = cc & 15, cbase = cc * 32;
    #pragma unroll 1
    for (int s = 0; s < 4; ++s) {
        if (q == s) {
            #pragma unroll
            for (int j = 0; j < 16; ++j) {
                *(v2f*)&tw[(2 * j) * 32 + 2 * (g ^ ((2 * j) & 15))]         = mk2(y0[j].x, y1[j].x);
                *(v2f*)&tw[(2 * j + 1) * 32 + 2 * (g ^ ((2 * j + 1) & 15))] = mk2(y0[j].y, y1[j].y);
            }
        }
        wave_fence();
        v2f yc[16];
        #pragma unroll
        for (int p2 = 0; p2 < 16; ++p2)
            yc[p2] = *(const v2f*)&tw[cbase + 2 * (p2 ^ cm)];
        const size_t gmo = gmbase + s;
        #pragma unroll
        for (int i = 0; i < 16; ++i) {
            const int r = half * 16 + i;
            const int rw = r & 15;
            v2f acc = {0.f, 0.f};
            #pragma unroll
            for (int q8 = 0; q8 < 8; ++q8) {
                v4f f = *(const v4f*)&tw[r * 32 + 4 * q8];
                v2f lo = {f.x, f.y}, hi = {f.z, f.w};
                acc += lo * yc[(2 * q8) ^ rw] + hi * yc[(2 * q8 + 1) ^ rw];
            }
            out[gmo * 1024 + r * 32 + cc] = acc.x + acc.y;
        }
        wave_fence();
    }
}

extern "C" void kernel_launch(void* const* d_in, const int* in_sizes, int n_in,
                              void* d_out, int out_size, void* d_ws, size_t ws_size,
                              hipStream_t stream) {
    const float* X = (const float*)d_in[0];
    const float* R = (const float*)d_in[1];
    const float* B = (const float*)d_in[2];
    float* out = (float*)d_out;
    float* ws  = (float*)d_ws;

    hipMemsetAsync(d_ws, 0, WS_TOTAL * sizeof(float), stream);
    k_mean1<<<NMAT / 16, 256, 0, stream>>>(X, out);   // out free as scratch here
    k_mean2<<<4, 256, 0, stream>>>(out, ws);
    k_small_prep<<<2, 64, 0, stream>>>(R, B, ws);
    k_batch_log<<<NMAT / 16, 256, 0, stream>>>(X, out, ws);
    k_karcher<<<1, 64, 0, stream>>>(ws);
    k_fused<<<NMAT / 16, 256, 0, stream>>>(out, ws);
}

// Round 16
// 1648.035 us; speedup vs baseline: 2.8779x; 1.0020x over previous
//
#include <hip/hip_runtime.h>
#include <math.h>

typedef float v2f __attribute__((ext_vector_type(2)));
typedef float v4f __attribute__((ext_vector_type(4)));

#define NMAT 32768
#define SW1 4          // pass-1 sweeps (3 measured absmax 0.078 > 0.056 — min is 4)
#define SW2 2          // pass-2 sweeps (1 measured absmax 0.059 > 0.056 — min is 2)
#define SW_SINGLE 10   // single-matrix eigs
#define SP 34          // padded row stride for single-wave LDS matrices

// workspace float offsets
#define WS_G    0
#define WS_GS   1024
#define WS_GIS  2048
#define WS_GT   3072
#define WS_K    4096
#define WS_C    5120
#define WS_S1   6144
#define WS_S2   6145
#define WS_P    6146
#define WS_TOTAL 6400

__device__ __forceinline__ int swz(int r, int c) {
    return r * 32 + 2 * ((c >> 1) ^ (r & 15)) + (c & 1);
}
__device__ __forceinline__ void wave_fence() {
    asm volatile("s_waitcnt lgkmcnt(0)" ::: "memory");
}
__device__ __forceinline__ v2f mk2(float a, float b) { v2f r; r.x = a; r.y = b; return r; }

// xor-shuffle: CTRL!=0 -> VALU DPP (quad_perm m=1,2,3; row_half_mirror 0x141
// = lane^7; row_mirror 0x140 = lane^15 — verified working r13/r14).
// CTRL==0 -> DS shuffle.
template<int CTRL>
__device__ __forceinline__ float xsh(float x, int m) {
    if constexpr (CTRL != 0) {
        return __int_as_float(__builtin_amdgcn_update_dpp(
            __float_as_int(x), __float_as_int(x), CTRL, 0xF, 0xF, true));
    } else {
        return __shfl_xor(x, m, 64);
    }
}

__device__ __forceinline__ float nrm16(const v2f (&v)[16]) {
    v2f n0 = v[0] * v[0], n1 = v[1] * v[1], n2 = v[2] * v[2], n3 = v[3] * v[3];
    #pragma unroll
    for (int j = 4; j < 16; j += 4) {
        n0 += v[j] * v[j];     n1 += v[j + 1] * v[j + 1];
        n2 += v[j + 2] * v[j + 2]; n3 += v[j + 3] * v[j + 3];
    }
    v2f nt = (n0 + n1) + (n2 + n3);
    return nt.x + nt.y;
}

// ---------------------------------------------------------------------------
// Symmetric fast-Givens rotation on column pair (X,Y); deterministic d==0
// tie-break via `low` (partner computes !low -> t flips exactly).
// ---------------------------------------------------------------------------
__device__ __forceinline__ void rot2(v2f (&X)[16], v2f (&Y)[16],
                                     float& dnX, float& dnY,
                                     float& sX, float& rsX,
                                     float& sY, float& rsY, bool low) {
    v2f p0 = X[0] * Y[0], p1 = X[1] * Y[1], p2 = X[2] * Y[2], p3 = X[3] * Y[3];
    #pragma unroll
    for (int j = 4; j < 16; j += 4) {
        p0 += X[j] * Y[j];         p1 += X[j + 1] * Y[j + 1];
        p2 += X[j + 2] * Y[j + 2]; p3 += X[j + 3] * Y[j + 3];
    }
    v2f pt = (p0 + p1) + (p2 + p3);
    const float raw = pt.x + pt.y;
    const float apq = (sX * sY) * raw;
    const float b   = apq + apq;
    const float d   = dnY - dnX;
    const float r2  = __builtin_fmaf(d, d, b * b);
    const float sr  = __builtin_amdgcn_sqrtf(r2);
    const float u   = fmaxf(fabsf(d) + sr, 1e-30f);
    const bool  neg = (d < 0.f) || (d == 0.f && !low);
    const float t   = (neg ? -b : b) * __builtin_amdgcn_rcpf(u);
    const float s1f = __builtin_fmaf(t, t, 1.f);
    const float c   = __builtin_amdgcn_rsqf(s1f);
    const float rc  = c * s1f;
    const float gX  = -t * (sY * rsX);
    const float gY  =  t * (sX * rsY);
    const v2f gX2 = {gX, gX}, gY2 = {gY, gY};
    #pragma unroll
    for (int j = 0; j < 16; ++j) {
        const v2f yo = Y[j];
        Y[j] = yo + gY2 * X[j];
        X[j] = X[j] + gX2 * yo;
    }
    dnX = __builtin_fmaf(-t, apq, dnX);
    dnY = __builtin_fmaf( t, apq, dnY);
    sX *= c; rsX *= rc;
    sY *= c; rsY *= rc;
}

// One tournament meeting vs group g^m.
template<int CTRL>
__device__ __forceinline__ void meeting(v2f (&v0)[16], v2f (&v1)[16],
                                        float& dn0, float& dn1,
                                        float& s0, float& rs0,
                                        float& s1_, float& rs1, int m, int g) {
    const bool low = g < (g ^ m);
    v2f c0[16], c1[16];
    #pragma unroll
    for (int j = 0; j < 16; ++j) {
        c0[j].x = xsh<CTRL>(v0[j].x, m);
        c0[j].y = xsh<CTRL>(v0[j].y, m);
    }
    float cdn0 = xsh<CTRL>(dn0, m), cs0 = xsh<CTRL>(s0, m), crs0 = xsh<CTRL>(rs0, m);
    #pragma unroll
    for (int j = 0; j < 16; ++j) {
        c1[j].x = xsh<CTRL>(v1[j].x, m);
        c1[j].y = xsh<CTRL>(v1[j].y, m);
    }
    float cdn1 = xsh<CTRL>(dn1, m), cs1 = xsh<CTRL>(s1_, m), crs1 = xsh<CTRL>(rs1, m);
    rot2(v0, c0, dn0, cdn0, s0, rs0, cs0, crs0, low);
    rot2(v1, c1, dn1, cdn1, s1_, rs1, cs1, crs1, low);
    rot2(v0, c1, dn0, cdn1, s0, rs0, cs1, crs1, low);
    rot2(v1, c0, dn1, cdn0, s1_, rs1, cs0, crs0, low);
}

// ---------------------------------------------------------------------------
// Blocked one-sided Jacobi: lane owns cols {2g,2g+1}; 16 lanes/matrix;
// 4 matrices/wave. Masks 1,2,3,7,15 on VALU DPP; rest DS.
// ---------------------------------------------------------------------------
__device__ __forceinline__ void jacobi_blk(v2f (&v0)[16], v2f (&v1)[16], int g,
                                           int sweeps, float& odn0, float& odn1) {
    #pragma unroll 1
    for (int sw = 0; sw < sweeps; ++sw) {
        float dn0 = nrm16(v0), dn1 = nrm16(v1);
        float s0 = 1.f, rs0 = 1.f, s1_ = 1.f, rs1 = 1.f;
        rot2(v0, v1, dn0, dn1, s0, rs0, s1_, rs1, true);  // intra pair
        meeting<0xB1>(v0, v1, dn0, dn1, s0, rs0, s1_, rs1, 1, g);
        meeting<0x4E>(v0, v1, dn0, dn1, s0, rs0, s1_, rs1, 2, g);
        meeting<0x1B>(v0, v1, dn0, dn1, s0, rs0, s1_, rs1, 3, g);
        #pragma unroll 1
        for (int m = 4; m <= 6; ++m)
            meeting<0>(v0, v1, dn0, dn1, s0, rs0, s1_, rs1, m, g);
        meeting<0x141>(v0, v1, dn0, dn1, s0, rs0, s1_, rs1, 7, g);
        #pragma unroll 1
        for (int m = 8; m <= 14; ++m)
            meeting<0>(v0, v1, dn0, dn1, s0, rs0, s1_, rs1, m, g);
        meeting<0x140>(v0, v1, dn0, dn1, s0, rs0, s1_, rs1, 15, g);
        const v2f f0 = {s0, s0}, f1 = {s1_, s1_};
        #pragma unroll
        for (int j = 0; j < 16; ++j) { v0[j] *= f0; v1[j] *= f1; }
    }
    odn0 = nrm16(v0);
    odn1 = nrm16(v1);
}

// ---------------------------------------------------------------------------
// Single-wave 1-col Jacobi (k_small_prep / k_karcher only). r11-proven
// semantics: t computed identically on both lanes; sign asymmetry via isp.
// ---------------------------------------------------------------------------
template<int CTRL>
__device__ __forceinline__ void jac_round(v2f (&v)[16], int col, int m,
                                          float& dn, float& sc, float& rsc) {
    const float dnq = xsh<CTRL>(dn, m);
    const float dq  = xsh<CTRL>(sc, m);
    v2f o[16];
    #pragma unroll
    for (int j = 0; j < 16; ++j) {
        o[j].x = xsh<CTRL>(v[j].x, m);
        o[j].y = xsh<CTRL>(v[j].y, m);
    }
    v2f p0 = v[0] * o[0], p1 = v[1] * o[1], p2 = v[2] * o[2], p3 = v[3] * o[3];
    #pragma unroll
    for (int j = 4; j < 16; j += 4) {
        p0 += v[j] * o[j];     p1 += v[j + 1] * o[j + 1];
        p2 += v[j + 2] * o[j + 2]; p3 += v[j + 3] * o[j + 3];
    }
    v2f pt = (p0 + p1) + (p2 + p3);
    const float raw = pt.x + pt.y;
    const bool  isp = col < (col ^ m);
    const float apq = (sc * dq) * raw;
    const float b   = apq + apq;
    const float d   = isp ? (dnq - dn) : (dn - dnq);
    const float r2  = __builtin_fmaf(d, d, b * b);
    const float sr  = __builtin_amdgcn_sqrtf(r2);
    const float u   = fmaxf(fabsf(d) + sr, 1e-30f);
    const float t   = (d < 0.f ? -b : b) * __builtin_amdgcn_rcpf(u);
    const float s1  = __builtin_fmaf(t, t, 1.f);
    const float c   = __builtin_amdgcn_rsqf(s1);
    const float gam = t * (dq * rsc);
    const float gs  = isp ? -gam : gam;
    const v2f gs2 = {gs, gs};
    #pragma unroll
    for (int j = 0; j < 16; ++j) v[j] += gs2 * o[j];
    sc *= c; rsc *= c * s1;
    dn = __builtin_fmaf(isp ? -t : t, apq, dn);
}

__device__ __forceinline__ float jacobi_fg(v2f (&v)[16], int col, int sweeps) {
    #pragma unroll 1
    for (int sweep = 0; sweep < sweeps; ++sweep) {
        float dn = nrm16(v);
        float sc = 1.f, rsc = 1.f;
        jac_round<0xB1>(v, col, 1, dn, sc, rsc);
        jac_round<0x4E>(v, col, 2, dn, sc, rsc);
        jac_round<0x1B>(v, col, 3, dn, sc, rsc);
        #pragma unroll 1
        for (int m = 4; m <= 6; ++m) jac_round<0>(v, col, m, dn, sc, rsc);
        jac_round<0x141>(v, col, 7, dn, sc, rsc);
        #pragma unroll 1
        for (int m = 8; m <= 14; ++m) jac_round<0>(v, col, m, dn, sc, rsc);
        jac_round<0x140>(v, col, 15, dn, sc, rsc);
        #pragma unroll 1
        for (int m = 16; m < 32; ++m) jac_round<0>(v, col, m, dn, sc, rsc);
        const v2f s2 = {sc, sc};
        #pragma unroll
        for (int j = 0; j < 16; ++j) v[j] *= s2;
    }
    return nrm16(v);
}

__device__ __forceinline__ void put_col(float* L, const v2f (&w)[16], int col) {
    #pragma unroll
    for (int j = 0; j < 16; ++j) {
        L[(2 * j) * SP + col]     = w[j].x;
        L[(2 * j + 1) * SP + col] = w[j].y;
    }
}

__device__ __forceinline__ void colmm(const float* L, const v2f (&y)[16], v2f (&z)[16]) {
    #pragma unroll
    for (int i = 0; i < 32; ++i) {
        v2f acc = {0.f, 0.f};
        #pragma unroll
        for (int q = 0; q < 16; ++q) {
            v2f mm = *(const v2f*)&L[i * SP + 2 * q];
            acc += mm * y[q];
        }
        float zi = acc.x + acc.y;
        if (i & 1) z[i >> 1].y = zi; else z[i >> 1].x = zi;
    }
}

__device__ __forceinline__ void recon_col(const float* LW, float coef, int col,
                                          int base, v2f (&z)[16]) {
    float rv[32];
    #pragma unroll
    for (int k = 0; k < 32; ++k) rv[k] = LW[col * SP + k];
    v2f y[16];
    #pragma unroll
    for (int q = 0; q < 16; ++q) {
        y[q].x = __shfl(coef, base | (2 * q), 64)     * rv[2 * q];
        y[q].y = __shfl(coef, base | (2 * q + 1), 64) * rv[2 * q + 1];
    }
    colmm(LW, y, z);
}

// ---------------------------------------------------------------------------
// K1a: per-block partial sums of 16 matrices -> scratch (d_out, free here)
// ---------------------------------------------------------------------------
__global__ __launch_bounds__(256) void k_mean1(const float* __restrict__ X,
                                               float* __restrict__ scratch) {
    const int t = threadIdx.x;
    const size_t base = (size_t)blockIdx.x * 16 * 1024;
    float4 a = {0.f, 0.f, 0.f, 0.f};
    for (int m = 0; m < 16; ++m) {
        float4 f = *(const float4*)&X[base + (size_t)m * 1024 + t * 4];
        a.x += f.x; a.y += f.y; a.z += f.z; a.w += f.w;
    }
    *(float4*)&scratch[(size_t)blockIdx.x * 1024 + t * 4] = a;
}

// K1b: reduce 2048 partials -> ws[WS_G]
__global__ __launch_bounds__(256) void k_mean2(const float* __restrict__ scratch,
                                               float* __restrict__ ws) {
    const int e = blockIdx.x * 256 + threadIdx.x;   // 4 blocks x 256 = 1024
    float a = 0.f;
    for (int p = 0; p < 2048; ++p) a += scratch[(size_t)p * 1024 + e];
    ws[WS_G + e] = a * (1.0f / (float)NMAT);
}

// ---------------------------------------------------------------------------
// K2: block 0: eig(G) -> Gs, Gis.  block 1: eig(B) -> C = B^{1/2} R.
// ---------------------------------------------------------------------------
__global__ __launch_bounds__(64) void k_small_prep(const float* __restrict__ R,
                                                   const float* __restrict__ B,
                                                   float* __restrict__ ws) {
    __shared__ float LW[32 * SP];
    const int lane = threadIdx.x;
    const int col  = lane & 31;
    const int base = lane & 32;
    if (blockIdx.x == 0) {
        v2f w[16];
        #pragma unroll
        for (int j = 0; j < 16; ++j) {
            w[j].x = ws[WS_G + (2 * j) * 32 + col];
            w[j].y = ws[WS_G + (2 * j + 1) * 32 + col];
        }
        const float dn = jacobi_fg(w, col, SW_SINGLE);
        put_col(LW, w, col);
        __syncthreads();
        const float lam = __builtin_amdgcn_sqrtf(dn);
        const float cs  = __builtin_amdgcn_sqrtf(lam) * __builtin_amdgcn_rcpf(dn);
        const float cis = __builtin_amdgcn_rsqf(lam)  * __builtin_amdgcn_rcpf(dn);
        v2f z[16];
        recon_col(LW, cs, col, base, z);
        #pragma unroll
        for (int j = 0; j < 16; ++j) {
            ws[WS_GS + (2 * j) * 32 + col]     = z[j].x;
            ws[WS_GS + (2 * j + 1) * 32 + col] = z[j].y;
        }
        recon_col(LW, cis, col, base, z);
        #pragma unroll
        for (int j = 0; j < 16; ++j) {
            ws[WS_GIS + (2 * j) * 32 + col]     = z[j].x;
            ws[WS_GIS + (2 * j + 1) * 32 + col] = z[j].y;
        }
    } else {
        v2f w[16];
        #pragma unroll
        for (int j = 0; j < 16; ++j) {
            w[j].x = B[(2 * j) * 32 + col];
            w[j].y = B[(2 * j + 1) * 32 + col];
        }
        const float dn = jacobi_fg(w, col, SW_SINGLE);
        put_col(LW, w, col);
        __syncthreads();
        const float lam = __builtin_amdgcn_sqrtf(dn);
        const float cbs = __builtin_amdgcn_sqrtf(lam) * __builtin_amdgcn_rcpf(dn);
        v2f bs[16];
        recon_col(LW, cbs, col, base, bs);
        __syncthreads();
        put_col(LW, bs, col);
        __syncthreads();
        v2f r[16];
        #pragma unroll
        for (int j = 0; j < 16; ++j) {
            r[j].x = R[(2 * j) * 32 + col];
            r[j].y = R[(2 * j + 1) * 32 + col];
        }
        v2f c[16];
        colmm(LW, r, c);
        #pragma unroll
        for (int j = 0; j < 16; ++j) {
            ws[WS_C + (2 * j) * 32 + col]     = c[j].x;
            ws[WS_C + (2 * j + 1) * 32 + col] = c[j].y;
        }
    }
}

// ---------------------------------------------------------------------------
// K3 (pass 1): M = Gis X Gis; blocked Jacobi (4 mat/wave); W1 -> w1out;
// GT/S1/S2 accumulation.
// ---------------------------------------------------------------------------
__global__ __launch_bounds__(256) void k_batch_log(const float* __restrict__ X,
                                                   float* __restrict__ w1out,
                                                   float* __restrict__ ws) {
    __shared__ float HL[1024];       // Gis, pair-swizzled
    __shared__ float TW[4][1024];    // per-wave take-turns W tile
    __shared__ float GB[4][4][32];   // per-wave, per-stage g coefficients
    __shared__ float ACC[1024];
    __shared__ float S1B, S2B;
    const int tid = threadIdx.x;
    if (tid == 0) { S1B = 0.f; S2B = 0.f; }
    for (int e = tid; e < 1024; e += 256) {
        int r = e >> 5, c = e & 31;
        HL[swz(r, c)] = ws[WS_GIS + e];
        ACC[e] = 0.f;
    }
    __syncthreads();

    const int lane = tid & 63;
    const int wv   = tid >> 6;
    const int q    = lane >> 4;          // matrix quarter within wave
    const int g    = lane & 15;          // group (owns cols 2g, 2g+1)
    const int c0   = 2 * g;
    const size_t gm = (size_t)blockIdx.x * 16 + wv * 4 + q;
    const float* Xm = X + gm * 1024;
    float* tw = TW[wv];

    v2f v0[16], v1[16];
    {   // congruence temporaries scoped
        v2f h0[16], h1[16];
        const int e0 = c0 & 15, e1 = (c0 + 1) & 15;
        #pragma unroll
        for (int p = 0; p < 16; ++p) {
            h0[p] = *(const v2f*)&HL[c0 * 32 + 2 * (p ^ e0)];
            h1[p] = *(const v2f*)&HL[(c0 + 1) * 32 + 2 * (p ^ e1)];
        }
        v2f t0[16], t1[16];
        #pragma unroll
        for (int i = 0; i < 32; ++i) {
            const float4* row = (const float4*)(Xm + i * 32);
            v2f a0 = {0.f, 0.f}, a1 = {0.f, 0.f};
            #pragma unroll
            for (int q8 = 0; q8 < 8; ++q8) {
                float4 f = row[q8];
                v2f lo = {f.x, f.y}, hi = {f.z, f.w};
                a0 += lo * h0[2 * q8] + hi * h0[2 * q8 + 1];
                a1 += lo * h1[2 * q8] + hi * h1[2 * q8 + 1];
            }
            float u0 = a0.x + a0.y, u1 = a1.x + a1.y;
            if (i & 1) { t0[i >> 1].y = u0; t1[i >> 1].y = u1; }
            else       { t0[i >> 1].x = u0; t1[i >> 1].x = u1; }
        }
        #pragma unroll
        for (int i = 0; i < 32; ++i) {
            const int twi = i & 15;
            v2f a0 = {0.f, 0.f}, a1 = {0.f, 0.f};
            #pragma unroll
            for (int q8 = 0; q8 < 8; ++q8) {
                v4f f = *(const v4f*)&HL[i * 32 + 4 * q8];
                v2f lo = {f.x, f.y}, hi = {f.z, f.w};
                a0 += lo * t0[(2 * q8) ^ twi] + hi * t0[(2 * q8 + 1) ^ twi];
                a1 += lo * t1[(2 * q8) ^ twi] + hi * t1[(2 * q8 + 1) ^ twi];
            }
            float u0 = a0.x + a0.y, u1 = a1.x + a1.y;
            if (i & 1) { v0[i >> 1].y = u0; v1[i >> 1].y = u1; }
            else       { v0[i >> 1].x = u0; v1[i >> 1].x = u1; }
        }
    }

    float dn0, dn1;
    jacobi_blk(v0, v1, g, SW1, dn0, dn1);

    // W1 -> global (row-pair v2f stores)
    float* op = w1out + gm * 1024 + c0;
    #pragma unroll
    for (int j = 0; j < 16; ++j) {
        *(v2f*)&op[(2 * j) * 32]     = mk2(v0[j].x, v1[j].x);
        *(v2f*)&op[(2 * j + 1) * 32] = mk2(v0[j].y, v1[j].y);
    }

    // log-eigen stats
    const float ls0 = 0.5f * logf(dn0), ls1 = 0.5f * logf(dn1);
    const float invN = 1.0f / (float)NMAT;
    const float g0 = ls0 * __builtin_amdgcn_rcpf(dn0) * invN;
    const float g1 = ls1 * __builtin_amdgcn_rcpf(dn1) * invN;
    {
        float s1v = ls0 + ls1, s2v = ls0 * ls0 + ls1 * ls1;
        #pragma unroll
        for (int m = 32; m >= 1; m >>= 1) {
            s1v += __shfl_xor(s1v, m, 64);
            s2v += __shfl_xor(s2v, m, 64);
        }
        if (lane == 0) { atomicAdd(&S1B, s1v); atomicAdd(&S2B, s2v); }
    }

    // GT recon: 4-stage take-turns tile per wave
    float accR[16];
    #pragma unroll
    for (int i = 0; i < 16; ++i) accR[i] = 0.f;
    const int cc = lane & 31, half = lane >> 5;
    const int cm = cc & 15, cbase = cc * 32;

    #pragma unroll 1
    for (int s = 0; s < 4; ++s) {
        if (q == s) {
            #pragma unroll
            for (int j = 0; j < 16; ++j) {
                *(v2f*)&tw[(2 * j) * 32 + 2 * (g ^ ((2 * j) & 15))]         = mk2(v0[j].x, v1[j].x);
                *(v2f*)&tw[(2 * j + 1) * 32 + 2 * (g ^ ((2 * j + 1) & 15))] = mk2(v0[j].y, v1[j].y);
            }
            *(v2f*)&GB[wv][s][c0] = mk2(g0, g1);
        }
        wave_fence();
        v2f gr[16];
        #pragma unroll
        for (int p2 = 0; p2 < 16; ++p2) {
            v2f wr = *(const v2f*)&tw[cbase + 2 * (p2 ^ cm)];
            v2f gg = *(const v2f*)&GB[wv][s][2 * p2];
            gr[p2] = gg * wr;
        }
        #pragma unroll
        for (int i = 0; i < 16; ++i) {
            const int r = half * 16 + i;
            const int rw = r & 15;
            v2f acc = {0.f, 0.f};
            #pragma unroll
            for (int q8 = 0; q8 < 8; ++q8) {
                v4f f = *(const v4f*)&tw[r * 32 + 4 * q8];
                v2f lo = {f.x, f.y}, hi = {f.z, f.w};
                acc += lo * gr[(2 * q8) ^ rw] + hi * gr[(2 * q8 + 1) ^ rw];
            }
            accR[i] += acc.x + acc.y;
        }
        wave_fence();
    }
    #pragma unroll
    for (int i = 0; i < 16; ++i)
        atomicAdd(&ACC[(half * 16 + i) * 32 + cc], accR[i]);
    __syncthreads();
    for (int e = tid; e < 1024; e += 256) atomicAdd(ws + WS_GT + e, ACC[e]);
    if (tid == 0) {
        atomicAdd(ws + WS_S1, S1B * invN);
        atomicAdd(ws + WS_S2, S2B * invN);
    }
}

// ---------------------------------------------------------------------------
// K4: E = exp(GT); Gn = Gs E Gs; Gh = Gn^{-1/2}; K = Gh*Gs; p from S1,S2.
// ---------------------------------------------------------------------------
__global__ __launch_bounds__(64) void k_karcher(float* __restrict__ ws) {
    __shared__ float LA[32 * SP];
    __shared__ float LB[32 * SP];
    const int lane = threadIdx.x;
    const int col  = lane & 31;
    const int base = lane & 32;

    for (int e = lane; e < 1024; e += 64)
        LB[(e >> 5) * SP + (e & 31)] = ws[WS_GS + e];
    v2f gsc[16];
    #pragma unroll
    for (int j = 0; j < 16; ++j) {
        gsc[j].x = ws[WS_GS + (2 * j) * 32 + col];
        gsc[j].y = ws[WS_GS + (2 * j + 1) * 32 + col];
    }
    v2f w[16];
    #pragma unroll
    for (int j = 0; j < 16; ++j) {
        w[j].x = ws[WS_GT + (2 * j) * 32 + col];
        w[j].y = ws[WS_GT + (2 * j + 1) * 32 + col];
    }
    v2f cn2 = {0.f, 0.f};
    #pragma unroll
    for (int j = 0; j < 16; ++j) cn2 += w[j] * w[j];
    float fro2 = cn2.x + cn2.y;
    #pragma unroll
    for (int m = 16; m >= 1; m >>= 1) fro2 += __shfl_xor(fro2, m, 64);
    const float shift = __builtin_amdgcn_sqrtf(fro2) + 0.01f;
    #pragma unroll
    for (int j = 0; j < 16; ++j) {
        w[j].x += (2 * j     == col) ? shift : 0.f;
        w[j].y += (2 * j + 1 == col) ? shift : 0.f;
    }
    const float dn = jacobi_fg(w, col, SW_SINGLE);
    put_col(LA, w, col);
    __syncthreads();
    const float lam = __builtin_amdgcn_sqrtf(dn) - shift;
    const float ce  = expf(lam) * __builtin_amdgcn_rcpf(dn);
    v2f ec[16];
    recon_col(LA, ce, col, base, ec);
    __syncthreads();
    put_col(LA, ec, col);
    __syncthreads();
    v2f u[16], gn[16];
    colmm(LA, gsc, u);
    colmm(LB, u, gn);
    const float dn2 = jacobi_fg(gn, col, SW_SINGLE);
    __syncthreads();
    put_col(LA, gn, col);
    __syncthreads();
    const float lam2 = __builtin_amdgcn_sqrtf(dn2);
    const float ch   = __builtin_amdgcn_rsqf(lam2) * __builtin_amdgcn_rcpf(dn2);
    v2f gh[16];
    recon_col(LA, ch, col, base, gh);
    __syncthreads();
    put_col(LA, gh, col);
    __syncthreads();
    v2f kc[16];
    colmm(LA, gsc, kc);
    #pragma unroll
    for (int j = 0; j < 16; ++j) {
        ws[WS_K + (2 * j) * 32 + col]     = kc[j].x;
        ws[WS_K + (2 * j + 1) * 32 + col] = kc[j].y;
    }
    if (lane == 0) {
        const float S1  = ws[WS_S1];
        const float S2  = ws[WS_S2];
        const float var = S2 - S1 * S1 * 0.03125f;
        ws[WS_P] = __builtin_amdgcn_rsqf(var + 1e-5f);
    }
}

// ---------------------------------------------------------------------------
// K5 (fused warm+final): F = K W1 diag(lam1^{-1/2}); blocked 2-sweep Jacobi;
// Y = C W2 diag(lam^{(p-1)/2}); out = Y Y^T (4-stage take-turns tile).
// ---------------------------------------------------------------------------
__global__ __launch_bounds__(256) void k_fused(float* __restrict__ out,
                                               const float* __restrict__ ws) {
    __shared__ float KL[1024];
    __shared__ float CL[1024];
    __shared__ float TW[4][1024];
    const int tid = threadIdx.x;
    for (int e = tid; e < 1024; e += 256) {
        KL[e] = ws[WS_K + e];
        CL[e] = ws[WS_C + e];
    }
    __syncthreads();

    const int lane = tid & 63;
    const int wv   = tid >> 6;
    const int q    = lane >> 4;
    const int g    = lane & 15;
    const int c0   = 2 * g;
    const size_t gmbase = (size_t)blockIdx.x * 16 + wv * 4;
    const size_t gm = gmbase + q;
    float* tw = TW[wv];
    const float p = ws[WS_P];

    v2f v0[16], v1[16];
    {   // load + scale + K-multiply scoped
        const float* wp = out + gm * 1024 + c0;
        v2f t0[16], t1[16];
        #pragma unroll
        for (int j = 0; j < 16; ++j) {
            v2f la = *(const v2f*)&wp[(2 * j) * 32];
            v2f lb = *(const v2f*)&wp[(2 * j + 1) * 32];
            t0[j] = mk2(la.x, lb.x);
            t1[j] = mk2(la.y, lb.y);
        }
        const float nn0 = nrm16(t0), nn1 = nrm16(t1);
        const float sc0 = __builtin_amdgcn_rsqf(__builtin_amdgcn_sqrtf(nn0));
        const float sc1 = __builtin_amdgcn_rsqf(__builtin_amdgcn_sqrtf(nn1));
        const v2f sv0 = {sc0, sc0}, sv1 = {sc1, sc1};
        #pragma unroll
        for (int j = 0; j < 16; ++j) { t0[j] *= sv0; t1[j] *= sv1; }
        #pragma unroll
        for (int i = 0; i < 32; ++i) {
            v2f a0 = {0.f, 0.f}, a1 = {0.f, 0.f};
            #pragma unroll
            for (int q8 = 0; q8 < 8; ++q8) {
                v4f f = *(const v4f*)&KL[i * 32 + 4 * q8];
                v2f lo = {f.x, f.y}, hi = {f.z, f.w};
                a0 += lo * t0[2 * q8] + hi * t0[2 * q8 + 1];
                a1 += lo * t1[2 * q8] + hi * t1[2 * q8 + 1];
            }
            float u0 = a0.x + a0.y, u1 = a1.x + a1.y;
            if (i & 1) { v0[i >> 1].y = u0; v1[i >> 1].y = u1; }
            else       { v0[i >> 1].x = u0; v1[i >> 1].x = u1; }
        }
    }

    float dn0, dn1;
    jacobi_blk(v0, v1, g, SW2, dn0, dn1);   // dn = lambda (factor form)

    const float dj0 = exp2f(log2f(dn0) * 0.5f * (p - 1.0f));
    const float dj1 = exp2f(log2f(dn1) * 0.5f * (p - 1.0f));
    const v2f dv0 = {dj0, dj0}, dv1 = {dj1, dj1};
    v2f y0[16], y1[16];
    {
        v2f t0[16], t1[16];
        #pragma unroll
        for (int j = 0; j < 16; ++j) { t0[j] = v0[j] * dv0; t1[j] = v1[j] * dv1; }
        #pragma unroll
        for (int i = 0; i < 32; ++i) {
            v2f a0 = {0.f, 0.f}, a1 = {0.f, 0.f};
            #pragma unroll
            for (int q8 = 0; q8 < 8; ++q8) {
                v4f f = *(const v4f*)&CL[i * 32 + 4 * q8];
                v2f lo = {f.x, f.y}, hi = {f.z, f.w};
                a0 += lo * t0[2 * q8] + hi * t0[2 * q8 + 1];
                a1 += lo * t1[2 * q8] + hi * t1[2 * q8 + 1];
            }
            float u0 = a0.x + a0.y, u1 = a1.x + a1.y;
            if (i & 1) { y0[i >> 1].y = u0; y1[i >> 1].y = u1; }
            else       { y0[i >> 1].x = u0; y1[i >> 1].x = u1; }
        }
    }

    // out = Y Y^T, 4-stage take-turns tile
    const int cc = lane & 31, half = lane >> 5;
    const int cm = cc & 15, cbase = cc * 32;
    #pragma unroll 1
    for (int s = 0; s < 4; ++s) {
        if (q == s) {
            #pragma unroll
            for (int j = 0; j < 16; ++j) {
                *(v2f*)&tw[(2 * j) * 32 + 2 * (g ^ ((2 * j) & 15))]         = mk2(y0[j].x, y1[j].x);
                *(v2f*)&tw[(2 * j + 1) * 32 + 2 * (g ^ ((2 * j + 1) & 15))] = mk2(y0[j].y, y1[j].y);
            }
        }
        wave_fence();
        v2f yc[16];
        #pragma unroll
        for (int p2 = 0; p2 < 16; ++p2)
            yc[p2] = *(const v2f*)&tw[cbase + 2 * (p2 ^ cm)];
        const size_t gmo = gmbase + s;
        #pragma unroll
        for (int i = 0; i < 16; ++i) {
            const int r = half * 16 + i;
            const int rw = r & 15;
            v2f acc = {0.f, 0.f};
            #pragma unroll
            for (int q8 = 0; q8 < 8; ++q8) {
                v4f f = *(const v4f*)&tw[r * 32 + 4 * q8];
                v2f lo = {f.x, f.y}, hi = {f.z, f.w};
                acc += lo * yc[(2 * q8) ^ rw] + hi * yc[(2 * q8 + 1) ^ rw];
            }
            out[gmo * 1024 + r * 32 + cc] = acc.x + acc.y;
        }
        wave_fence();
    }
}

extern "C" void kernel_launch(void* const* d_in, const int* in_sizes, int n_in,
                              void* d_out, int out_size, void* d_ws, size_t ws_size,
                              hipStream_t stream) {
    const float* X = (const float*)d_in[0];
    const float* R = (const float*)d_in[1];
    const float* B = (const float*)d_in[2];
    float* out = (float*)d_out;
    float* ws  = (float*)d_ws;

    hipMemsetAsync(d_ws, 0, WS_TOTAL * sizeof(float), stream);
    k_mean1<<<NMAT / 16, 256, 0, stream>>>(X, out);   // out free as scratch here
    k_mean2<<<4, 256, 0, stream>>>(out, ws);
    k_small_prep<<<2, 64, 0, stream>>>(R, B, ws);
    k_batch_log<<<NMAT / 16, 256, 0, stream>>>(X, out, ws);
    k_karcher<<<1, 64, 0, stream>>>(ws);
    k_fused<<<NMAT / 16, 256, 0, stream>>>(out, ws);
}